// Round 16
// baseline (512.431 us; speedup 1.0000x reference)
//
#include <hip/hip_runtime.h>
#include <math.h>

#define Nn 20000
#define Ee 120000
#define EALLe 240000
#define Cc 150
#define Rr 1000
#define EHd 300
#define RHd 100
#define CHd 150
#define CB 128
#define XSPL 16
#define CAP 1600

static inline int cdiv_h(int a, int b){ return (a + b - 1) / b; }

typedef __attribute__((ext_vector_type(8))) short short8;
typedef __attribute__((ext_vector_type(4))) float f32x4;

__device__ __forceinline__ float lrelu01(float x){ return x > 0.f ? x : 0.01f * x; }

__device__ __forceinline__ unsigned short f2b(float f){
  unsigned int u = __float_as_uint(f);
  unsigned int r = (u + 0x7FFFu + ((u >> 16) & 1u)) >> 16;
  return (unsigned short)r;
}
__device__ __forceinline__ float b2f(unsigned short u){
  return __uint_as_float(((unsigned int)u) << 16);
}
__device__ __forceinline__ float b2f_lo(unsigned int u){
  return __uint_as_float(u << 16);
}
__device__ __forceinline__ float b2f_hi(unsigned int u){
  return __uint_as_float(u & 0xFFFF0000u);
}

template<int Kq>
__device__ __forceinline__ void wredsumN(float* v){
#pragma unroll
  for (int m = 32; m >= 1; m >>= 1){
#pragma unroll
    for (int k = 0; k < Kq; k++) v[k] += __shfl_xor(v[k], m, 64);
  }
}

__global__ __launch_bounds__(64) void k_f2b(const float* __restrict__ src, int ncols,
    int ldsrc, unsigned short* __restrict__ dst, int ldp){
  int r = blockIdx.x, t = threadIdx.x;
  for (int c = t; c < ldp; c += 64)
    dst[(size_t)r * ldp + c] = (c < ncols) ? f2b(src[(size_t)r * ldsrc + c]) : (unsigned short)0;
}

struct Cvt8 {
  const float* s[8];
  unsigned short* d[8];
  int nc[8]; int lds[8]; int ldp[8]; int r0[9];
};
__global__ __launch_bounds__(64) void k_f2ball(Cvt8 c){
  int b = blockIdx.x, t = threadIdx.x;
  int idx = 0;
#pragma unroll
  for (int q = 1; q < 8; q++) if (b >= c.r0[q]) idx = q;
  int r = b - c.r0[idx];
  const float* src = c.s[idx] + (size_t)r * c.lds[idx];
  unsigned short* dst = c.d[idx] + (size_t)r * c.ldp[idx];
  int nc = c.nc[idx], ldp = c.ldp[idx];
  for (int col = t; col < ldp; col += 64)
    dst[col] = (col < nc) ? f2b(src[col]) : (unsigned short)0;
}

__global__ __launch_bounds__(64) void k_rnorm(const float* __restrict__ rt,
    const float* __restrict__ arh, const float* __restrict__ are,
    float* __restrict__ ra1h, float* __restrict__ ra1e){
  int r = blockIdx.x, lane = threadIdx.x;
  bool m1 = (lane + 64 < RHd);
  float v0 = rt[r * RHd + lane];
  float v1 = m1 ? rt[r * RHd + lane + 64] : 0.f;
  float s[3];
  s[0] = v0 * v0 + v1 * v1;
  s[1] = v0 * arh[RHd + lane] + (m1 ? v1 * arh[RHd + lane + 64] : 0.f);
  s[2] = v0 * are[RHd + lane] + (m1 ? v1 * are[RHd + lane + 64] : 0.f);
  wredsumN<3>(s);
  float inv = 0.5f / fmaxf(sqrtf(s[0]), 1e-12f);
  if (!lane){
    ra1h[r] = s[1] * inv;
    ra1e[r] = s[2] * inv;
  }
}

__global__ void k_count(const int* __restrict__ dst, int* __restrict__ degi){
  int e = blockIdx.x * blockDim.x + threadIdx.x;
  if (e < EALLe) atomicAdd(&degi[dst[e]], 1);
}

__global__ __launch_bounds__(1024) void k_scan(const int* __restrict__ degi,
    int* __restrict__ ptr, int* __restrict__ cur, float* __restrict__ dis){
  __shared__ int s[1024];
  int t = threadIdx.x;
  const int per = (Nn + 1023) / 1024;
  int b0 = t * per; if (b0 > Nn) b0 = Nn;
  int b1 = b0 + per; if (b1 > Nn) b1 = Nn;
  int sum = 0;
  for (int i = b0; i < b1; i++) sum += degi[i];
  s[t] = sum;
  __syncthreads();
  for (int off = 1; off < 1024; off <<= 1){
    int v = (t >= off) ? s[t - off] : 0;
    __syncthreads();
    s[t] += v;
    __syncthreads();
  }
  int run = (t > 0) ? s[t - 1] : 0;
  for (int i = b0; i < b1; i++){
    int dg = degi[i];
    ptr[i] = run; cur[i] = run; run += dg;
    dis[i] = dg > 0 ? rsqrtf((float)dg) : 0.f;
  }
  if (t == 1023) ptr[Nn] = s[1023];
}

__global__ void k_scatter(const int* __restrict__ src, const int* __restrict__ dst,
    int* __restrict__ cur, int* __restrict__ csr_src){
  int e = blockIdx.x * blockDim.x + threadIdx.x;
  if (e >= EALLe) return;
  int pos = atomicAdd(&cur[dst[e]], 1);
  csr_src[pos] = src[e];
}

// GCN SpMM + relu, float4 gathers, 2-deep unroll for ILP
__global__ __launch_bounds__(256) void k_gcn4(const unsigned short* __restrict__ x,
    const int* __restrict__ ptr, const int* __restrict__ src,
    const float* __restrict__ dis, float* __restrict__ out){
  __shared__ float wl[128];
  __shared__ int jl[128];
  __shared__ float red[5][40][8];
  int i = blockIdx.x, t = threadIdx.x;
  int p0 = ptr[i], p1 = ptr[i + 1];
  float* orow = out + (size_t)i * 300;
  if (p0 == p1){
    for (int f = t; f < 300; f += 256) orow[f] = 0.f;
    return;
  }
  int g = t / 40, c = t - g * 40;
  bool act = t < 240;
  float di = dis[i];
  float acc[8] = {};
  for (int base = p0; base < p1; base += 128){
    int k = base + t;
    if (t < 128 && k < p1){
      int j = src[k];
      jl[t] = j;
      wl[t] = di * dis[j];
    }
    __syncthreads();
    int lim = p1 - base; if (lim > 128) lim = 128;
    if (act){
      int q = g;
      for (; q + 6 < lim; q += 12){
        float w0 = wl[q], w1 = wl[q + 6];
        const unsigned short* x0 = x + (size_t)jl[q] * 320;
        const unsigned short* x1p = x + (size_t)jl[q + 6] * 320;
        union { f32x4 f; unsigned int u[4]; } U0, U1;
        U0.f = *(const f32x4*)&x0[8 * c];
        U1.f = *(const f32x4*)&x1p[8 * c];
#pragma unroll
        for (int h = 0; h < 4; h++){
          acc[2 * h]     += w0 * b2f_lo(U0.u[h]) + w1 * b2f_lo(U1.u[h]);
          acc[2 * h + 1] += w0 * b2f_hi(U0.u[h]) + w1 * b2f_hi(U1.u[h]);
        }
      }
      for (; q < lim; q += 6){
        float w = wl[q];
        const unsigned short* xr = x + (size_t)jl[q] * 320;
        union { f32x4 f; unsigned int u[4]; } U;
        U.f = *(const f32x4*)&xr[8 * c];
#pragma unroll
        for (int h = 0; h < 4; h++){
          acc[2 * h]     += w * b2f_lo(U.u[h]);
          acc[2 * h + 1] += w * b2f_hi(U.u[h]);
        }
      }
    }
    __syncthreads();
  }
  if (act && g > 0){
#pragma unroll
    for (int h = 0; h < 8; h++) red[g - 1][c][h] = acc[h];
  }
  __syncthreads();
  if (g == 0){
#pragma unroll
    for (int h = 0; h < 8; h++){
      float v = acc[h];
#pragma unroll
      for (int r = 0; r < 5; r++) v += red[r][c][h];
      acc[h] = fmaxf(v, 0.f);
    }
    int col0 = 8 * c;
    if (col0 + 8 <= 300){
      f32x4 o0 = { acc[0], acc[1], acc[2], acc[3] };
      f32x4 o1 = { acc[4], acc[5], acc[6], acc[7] };
      *(f32x4*)&orow[col0] = o0;
      *(f32x4*)&orow[col0 + 4] = o1;
    } else {
      for (int h = 0; h < 8 && col0 + h < 300; h++) orow[col0 + h] = acc[h];
    }
  }
}

// final GAT: fused x-copy + in-LDS edge weights + float4 gathers, 2-deep unroll
__global__ __launch_bounds__(256) void k_gat4(const float* __restrict__ x1,
    const unsigned short* __restrict__ x1b,
    const int* __restrict__ ptr, const int* __restrict__ src,
    const float* __restrict__ s1, const float* __restrict__ s2,
    float* __restrict__ dout){
  __shared__ float wl[128];
  __shared__ int jl[128];
  __shared__ float red[2][75][8];
  int i = blockIdx.x, t = threadIdx.x;
  float* orow = dout + (size_t)i * 900;
  const float* xi = x1 + (size_t)i * 600;
  if (t < 75) ((f32x4*)orow)[t] = ((const f32x4*)xi)[t];
  int p0 = ptr[i], p1 = ptr[i + 1];
  if (p0 == p1){
    for (int f = t; f < 600; f += 256) orow[300 + f] = 0.f;
    return;
  }
  float s1i = s1[i];
  int g = t / 75, c = t - g * 75;
  bool act = t < 225;
  float acc[8] = {};
  float den = 0.f;
  for (int base = p0; base < p1; base += 128){
    int k = base + t;
    if (t < 128 && k < p1){
      int j = src[k];
      jl[t] = j;
      wl[t] = expf(lrelu01(s1i + s2[j]));
    }
    __syncthreads();
    int lim = p1 - base; if (lim > 128) lim = 128;
    for (int q = 0; q < lim; q++) den += wl[q];
    if (act){
      int q = g;
      for (; q + 3 < lim; q += 6){
        float w0 = wl[q], w1 = wl[q + 3];
        const unsigned short* x0 = x1b + (size_t)jl[q] * 600;
        const unsigned short* x1p = x1b + (size_t)jl[q + 3] * 600;
        union { f32x4 f; unsigned int u[4]; } U0, U1;
        U0.f = *(const f32x4*)&x0[8 * c];
        U1.f = *(const f32x4*)&x1p[8 * c];
#pragma unroll
        for (int h = 0; h < 4; h++){
          acc[2 * h]     += w0 * b2f_lo(U0.u[h]) + w1 * b2f_lo(U1.u[h]);
          acc[2 * h + 1] += w0 * b2f_hi(U0.u[h]) + w1 * b2f_hi(U1.u[h]);
        }
      }
      for (; q < lim; q += 3){
        float w = wl[q];
        const unsigned short* xj = x1b + (size_t)jl[q] * 600;
        union { f32x4 f; unsigned int u[4]; } U;
        U.f = *(const f32x4*)&xj[8 * c];
#pragma unroll
        for (int h = 0; h < 4; h++){
          acc[2 * h]     += w * b2f_lo(U.u[h]);
          acc[2 * h + 1] += w * b2f_hi(U.u[h]);
        }
      }
    }
    __syncthreads();
  }
  if (act && g > 0){
#pragma unroll
    for (int h = 0; h < 8; h++) red[g - 1][c][h] = acc[h];
  }
  __syncthreads();
  if (g == 0){
    float invd = 1.f / den;
#pragma unroll
    for (int h = 0; h < 8; h++){
      float v = acc[h] + red[0][c][h] + red[1][c][h];
      acc[h] = fmaxf(v * invd, 0.f);
    }
    f32x4 o0 = { acc[0], acc[1], acc[2], acc[3] };
    f32x4 o1 = { acc[4], acc[5], acc[6], acc[7] };
    ((f32x4*)(orow + 300))[2 * c] = o0;
    ((f32x4*)(orow + 300))[2 * c + 1] = o1;
  }
}

// bf16 MFMA GEMM
template<int EPI, int MIR>
__global__ __launch_bounds__(256) void k_gemmb(
    const unsigned short* __restrict__ Xb, int ldxb, int nrows,
    const unsigned short* __restrict__ Wb, int Kp, int M,
    const float* __restrict__ bias,
    const float* __restrict__ X2, int ldx2,
    const float* __restrict__ Xf, int ldxf,
    float* __restrict__ out, int ldo,
    unsigned short* __restrict__ mir, int ldmir){
  __shared__ unsigned short Xs[64][40];
  __shared__ unsigned short Ws[64][40];
  int t = threadIdx.x;
  int wv = t >> 6, lane = t & 63;
  int c0 = blockIdx.x * 64, r0 = blockIdx.y * 64;
  int srow = t >> 2, skoff = (t & 3) * 8;
  int gxr = r0 + srow, gwr = c0 + srow;
  f32x4 acc[4] = {};
  for (int k0 = 0; k0 < Kp; k0 += 32){
    short8 xv = {0,0,0,0,0,0,0,0};
    short8 wv8 = {0,0,0,0,0,0,0,0};
    if (gxr < nrows) xv = *(const short8*)&Xb[(size_t)gxr * ldxb + k0 + skoff];
    if (gwr < M)     wv8 = *(const short8*)&Wb[(size_t)gwr * Kp + k0 + skoff];
    __syncthreads();
    *(short8*)&Xs[srow][skoff] = xv;
    *(short8*)&Ws[srow][skoff] = wv8;
    __syncthreads();
    int arow = wv * 16 + (lane & 15);
    int kk = (lane >> 4) * 8;
    short8 af = *(const short8*)&Xs[arow][kk];
#pragma unroll
    for (int j = 0; j < 4; j++){
      short8 bf = *(const short8*)&Ws[j * 16 + (lane & 15)][kk];
      acc[j] = __builtin_amdgcn_mfma_f32_16x16x32_bf16(af, bf, acc[j], 0, 0, 0);
    }
  }
  int rbase = r0 + wv * 16 + (lane >> 4) * 4;
  int cbase = c0 + (lane & 15);
#pragma unroll
  for (int j = 0; j < 4; j++){
    int c = cbase + j * 16;
    if (c >= M) continue;
#pragma unroll
    for (int r = 0; r < 4; r++){
      int row = rbase + r;
      if (row >= nrows) continue;
      float v = acc[j][r];
      float o;
      if (EPI == 0){
        o = fmaxf(v, 0.f);
      } else {
        float g = 1.f / (1.f + expf(-(v + bias[c])));
        o = g * X2[(size_t)row * ldx2 + c] + (1.f - g) * Xf[(size_t)row * ldxf + c];
      }
      out[(size_t)row * ldo + c] = o;
      if (MIR) mir[(size_t)row * ldmir + c] = f2b(o);
    }
  }
}

// batched gat_e highway GEMM
__global__ __launch_bounds__(256) void k_hwgemm(
    const unsigned short* __restrict__ xob,
    const unsigned short* __restrict__ hwwbA, const unsigned short* __restrict__ hwwbB,
    const float* __restrict__ hwbA, const float* __restrict__ hwbB,
    const float* __restrict__ outb, const float* __restrict__ proj,
    float* __restrict__ x1, unsigned short* __restrict__ x1b){
  __shared__ unsigned short Xs[64][40];
  __shared__ unsigned short Ws[64][40];
  int g = blockIdx.z;
  const unsigned short* Xb = xob + (size_t)g * Nn * 160;
  const unsigned short* Wb = g ? hwwbB : hwwbA;
  const float* bias = g ? hwbB : hwbA;
  const float* X2 = outb + (size_t)g * Nn * CHd;
  const float* Xf = proj + (g ? 450 : 0);
  float* outp = x1 + (g ? 450 : 300);
  unsigned short* mir = x1b + (g ? 450 : 300);
  int t = threadIdx.x;
  int wv = t >> 6, lane = t & 63;
  int c0 = blockIdx.x * 64, r0 = blockIdx.y * 64;
  int srow = t >> 2, skoff = (t & 3) * 8;
  int gxr = r0 + srow, gwr = c0 + srow;
  f32x4 acc[4] = {};
  for (int k0 = 0; k0 < 160; k0 += 32){
    short8 xv = {0,0,0,0,0,0,0,0};
    short8 wv8 = {0,0,0,0,0,0,0,0};
    if (gxr < Nn) xv = *(const short8*)&Xb[(size_t)gxr * 160 + k0 + skoff];
    if (gwr < 150) wv8 = *(const short8*)&Wb[(size_t)gwr * 160 + k0 + skoff];
    __syncthreads();
    *(short8*)&Xs[srow][skoff] = xv;
    *(short8*)&Ws[srow][skoff] = wv8;
    __syncthreads();
    int arow = wv * 16 + (lane & 15);
    int kk = (lane >> 4) * 8;
    short8 af = *(const short8*)&Xs[arow][kk];
#pragma unroll
    for (int j = 0; j < 4; j++){
      short8 bf = *(const short8*)&Ws[j * 16 + (lane & 15)][kk];
      acc[j] = __builtin_amdgcn_mfma_f32_16x16x32_bf16(af, bf, acc[j], 0, 0, 0);
    }
  }
  int rbase = r0 + wv * 16 + (lane >> 4) * 4;
  int cbase = c0 + (lane & 15);
#pragma unroll
  for (int j = 0; j < 4; j++){
    int c = cbase + j * 16;
    if (c >= 150) continue;
#pragma unroll
    for (int r = 0; r < 4; r++){
      int row = rbase + r;
      if (row >= Nn) continue;
      float v = acc[j][r];
      float gg = 1.f / (1.f + expf(-(v + bias[c])));
      float o = gg * X2[(size_t)row * CHd + c] + (1.f - gg) * Xf[(size_t)row * 600 + c];
      outp[(size_t)row * 600 + c] = o;
      mir[(size_t)row * 600 + c] = f2b(o);
    }
  }
}

// batched per-node precompute for both gat_e calls + fused xo->bf16 mirror
__global__ __launch_bounds__(64) void k_ndots2b(const float* __restrict__ proj,
    const float* __restrict__ h2r_ac, const float* __restrict__ et_ac,
    unsigned short* __restrict__ xob,
    unsigned short* __restrict__ xnb, float* __restrict__ pm,
    float* __restrict__ po, float* __restrict__ nv4){
  int n = blockIdx.x, g = blockIdx.y, lane = threadIdx.x;
  const float* ac = g ? et_ac : h2r_ac;
  const float* xm = proj + (g ? 300 : 150);
  const float* xo = proj + (g ? 450 : 0);
  const float* v2m = ac + (g ? 1 : 5) * CHd;
  const float* v2o = ac + (g ? 5 : 1) * CHd;
  const float* v3m = ac + (g ? 2 : 6) * CHd;
  const float* v3o = ac + (g ? 6 : 2) * CHd;
  const float* v4  = ac + 3 * CHd;
  bool m2 = lane < (CHd - 128);
  const float* mr = xm + (size_t)n * 600;
  const float* orw = xo + (size_t)n * 600;
  float m0 = mr[lane], m1 = mr[lane + 64], mv2 = m2 ? mr[lane + 128] : 0.f;
  float o0 = orw[lane], o1 = orw[lane + 64], o2 = m2 ? orw[lane + 128] : 0.f;
  unsigned short* xod = xob + (size_t)g * Nn * 160 + (size_t)n * 160;
  xod[lane] = f2b(o0);
  xod[lane + 64] = f2b(o1);
  if (m2) xod[lane + 128] = f2b(o2);
  if (lane < 10) xod[150 + lane] = 0;
  float s[4];
  s[0] = m0 * m0 + m1 * m1 + mv2 * mv2;
  s[1] = o0 * v2o[lane] + o1 * v2o[lane + 64] + (m2 ? o2 * v2o[lane + 128] : 0.f);
  s[2] = o0 * v3o[lane] + o1 * v3o[lane + 64] + (m2 ? o2 * v3o[lane + 128] : 0.f);
  s[3] = o0 * v4[lane]  + o1 * v4[lane + 64]  + (m2 ? o2 * v4[lane + 128]  : 0.f);
  wredsumN<4>(s);
  float inv = 1.f / fmaxf(sqrtf(s[0]), 1e-12f);
  float n0 = m0 * inv, n1 = m1 * inv, n2 = mv2 * inv;
  unsigned short* xr = xnb + (size_t)g * Nn * 152 + (size_t)n * 152;
  xr[lane] = f2b(n0); xr[lane + 64] = f2b(n1);
  if (m2) xr[lane + 128] = f2b(n2);
  float d[2];
  d[0] = n0 * v2m[lane] + n1 * v2m[lane + 64] + (m2 ? n2 * v2m[lane + 128] : 0.f);
  d[1] = n0 * v3m[lane] + n1 * v3m[lane + 64] + (m2 ? n2 * v3m[lane + 128] : 0.f);
  wredsumN<2>(d);
  if (!lane){
    pm[g * Nn + n] = d[0] + 0.25f * d[1];
    po[g * Nn + n] = s[1] + 0.25f * s[2];
    nv4[g * Nn + n] = s[3];
  }
}

// SINGLE-PASS edge kernel: exp-logit + class sums + direct class-bucket scatter.
// Fixed per-class capacity CAP; cstart is implicit (c*CAP); ccur holds totals.
__global__ __launch_bounds__(256) void k_edgescatter(const int* __restrict__ ei,
    const int* __restrict__ rel, const int* __restrict__ cih, const int* __restrict__ cit,
    const float* __restrict__ pm, const float* __restrict__ po,
    const float* __restrict__ ra1h, const float* __restrict__ ra1e,
    float* __restrict__ csum_p, int* __restrict__ ccur_p,
    int* __restrict__ crows, float* __restrict__ cw){
  __shared__ float ls[Cc];
  __shared__ int lcnt[Cc];
  __shared__ int lbase[Cc];
  int t = threadIdx.x, g = blockIdx.y;
  const int* im = ei + (g ? 0 : Ee);
  const int* io = ei + (g ? Ee : 0);
  const int* ci = g ? cit : cih;
  const float* ra1 = g ? ra1e : ra1h;
  const float* pmg = pm + g * Nn;
  const float* pog = po + g * Nn;
  float* csg = csum_p + g * Cc * 16;
  int* cug = ccur_p + g * Cc * 16;
  int* crg = crows + (size_t)g * Cc * CAP;
  float* cwg = cw + (size_t)g * Cc * CAP;
  int epb = (Ee + gridDim.x - 1) / gridDim.x;
  int e0 = blockIdx.x * epb, e1 = e0 + epb; if (e1 > Ee) e1 = Ee;
  for (int c = t; c < Cc; c += 256){ ls[c] = 0.f; lcnt[c] = 0; }
  __syncthreads();
  int myr[4], myc[4], myrow[4]; float myw[4]; int cnt = 0;
  for (int e = e0 + t; e < e1; e += 256){
    float v = lrelu01(pog[io[e]] + pmg[im[e]] + ra1[rel[e]]);
    float s = expf(v);
    int c = ci[e];
    atomicAdd(&ls[c], s);
    myr[cnt] = atomicAdd(&lcnt[c], 1);
    myc[cnt] = c; myw[cnt] = s; myrow[cnt] = im[im[e]];
    cnt++;
  }
  __syncthreads();
  for (int c = t; c < Cc; c += 256){
    if (lcnt[c]){
      lbase[c] = atomicAdd(&cug[c * 16], lcnt[c]);
      atomicAdd(&csg[c * 16], ls[c]);
    }
  }
  __syncthreads();
  for (int q = 0; q < cnt; q++){
    int c = myc[q];
    int pos = c * CAP + lbase[c] + myr[q];
    crg[pos] = myrow[q];
    cwg[pos] = myw[q];
  }
}

// class x_class accumulation: XSPL blocks per class; class range = [c*CAP, c*CAP+len)
__global__ __launch_bounds__(192) void k_xclassBb(
    const int* __restrict__ ccur_p, const int* __restrict__ crows,
    const float* __restrict__ cw, const float* __restrict__ csum_p,
    const unsigned short* __restrict__ xnb, float* __restrict__ x_class){
  int g = blockIdx.y;
  int c = blockIdx.x / XSPL, sp = blockIdx.x % XSPL;
  int t = threadIdx.x;
  const int* crg = crows + (size_t)g * Cc * CAP;
  const float* cwg = cw + (size_t)g * Cc * CAP;
  const unsigned short* xng = xnb + (size_t)g * Nn * 152;
  float* xcg = x_class + g * Cc * CHd;
  int len = ccur_p[g * Cc * 16 + c * 16];
  if (len <= 0) return;
  int chunk = (len + XSPL - 1) / XSPL;
  int q0 = c * CAP + sp * chunk;
  int q1 = q0 + chunk;
  int qend = c * CAP + len;
  if (q1 > qend) q1 = qend;
  if (q0 >= q1) return;
  bool act = t < CHd;
  float inv = 1.f / csum_p[g * Cc * 16 + c * 16];
  float acc = 0.f;
  int k = q0;
  for (; k + 4 <= q1; k += 4){
    int r0 = crg[k], r1 = crg[k + 1], r2 = crg[k + 2], r3 = crg[k + 3];
    float w0 = cwg[k] * inv, w1 = cwg[k + 1] * inv, w2 = cwg[k + 2] * inv, w3 = cwg[k + 3] * inv;
    if (act){
      acc += w0 * b2f(xng[(size_t)r0 * 152 + t]) + w1 * b2f(xng[(size_t)r1 * 152 + t])
           + w2 * b2f(xng[(size_t)r2 * 152 + t]) + w3 * b2f(xng[(size_t)r3 * 152 + t]);
    }
  }
  for (; k < q1; k++){
    if (act) acc += cwg[k] * inv * b2f(xng[(size_t)crg[k] * 152 + t]);
  }
  if (act) atomicAdd(&xcg[c * CHd + t], acc);
}

// merged class-final: wave-parallel dots -> LDS segment softmax -> parallel scatter.
// one block per call g.
__global__ __launch_bounds__(256) void k_cfinal(const float* __restrict__ x_class,
    const float* __restrict__ h2r_ac, const float* __restrict__ et_ac,
    const float* __restrict__ nv4,
    const int* __restrict__ hcls, const int* __restrict__ tcls,
    float* __restrict__ outb){
  __shared__ float v[Cc];
  __shared__ float gm[Cc];
  __shared__ int ce[Cc];
  int t = threadIdx.x, g = blockIdx.x;
  int wv = t >> 6, lane = t & 63;
  const float* xcg = x_class + (size_t)g * Cc * CHd;
  const float* acv = (g ? et_ac : h2r_ac) + 7 * CHd;
  const float* nvg = nv4 + g * Nn;
  const int* cls_ent = g ? tcls : hcls;
  float* obg = outb + (size_t)g * Nn * CHd;
  if (t < Cc) ce[t] = cls_ent[t];
  bool m2 = lane < (CHd - 128);
  for (int c = wv; c < Cc; c += 4){
    const float* xc = xcg + (size_t)c * CHd;
    float s[1];
    s[0] = xc[lane] * acv[lane] + xc[lane + 64] * acv[lane + 64]
         + (m2 ? xc[lane + 128] * acv[lane + 128] : 0.f);
    wredsumN<1>(s);
    if (!lane) v[c] = s[0];
  }
  __syncthreads();
  if (t < Cc){
    float vt = lrelu01(v[t] + nvg[ce[t]]);
    v[t] = vt;
  }
  __syncthreads();
  if (t < Cc){
    int sgm = ce[t];
    float m = -3.0e38f;
    for (int c2 = 0; c2 < Cc; c2++) if (ce[c2] == sgm) m = fmaxf(m, v[c2]);
    float sum = 0.f;
    for (int c2 = 0; c2 < Cc; c2++) if (ce[c2] == sgm) sum += expf(v[c2] - m);
    gm[t] = expf(v[t] - m) / sum;
  }
  __syncthreads();
  for (int idx = t; idx < Cc * CHd; idx += 256){
    int c = idx / CHd, f = idx - c * CHd;
    atomicAdd(&obg[(size_t)ce[c] * CHd + f], gm[c] * xcg[idx]);
  }
}

// per node dot of x1b row with gat_ai / gat_aj — dword loads
__global__ __launch_bounds__(64) void k_s12(const unsigned short* __restrict__ x1b,
    const float* __restrict__ ai, const float* __restrict__ aj,
    float* __restrict__ s1, float* __restrict__ s2){
  int n = blockIdx.x, lane = threadIdx.x;
  const unsigned int* xr = (const unsigned int*)(x1b + (size_t)n * 600);
  float sa = 0.f, sb = 0.f;
#pragma unroll
  for (int u = 0; u < 5; u++){
    int d = lane + u * 64;
    if (d < 300){
      unsigned int w = xr[d];
      float xlo = b2f_lo(w), xhi = b2f_hi(w);
      sa += xlo * ai[2 * d] + xhi * ai[2 * d + 1];
      sb += xlo * aj[2 * d] + xhi * aj[2 * d + 1];
    }
  }
  float s[2] = { sa, sb };
  wredsumN<2>(s);
  if (!lane){ s1[n] = s[0]; s2[n] = s[1]; }
}

extern "C" void kernel_launch(void* const* d_in, const int* in_sizes, int n_in,
                              void* d_out, int out_size, void* d_ws, size_t ws_size,
                              hipStream_t stream) {
  const float* x_e    = (const float*)d_in[0];
  const int*   ei     = (const int*)d_in[1];
  const int*   rel    = (const int*)d_in[2];
  const int*   eall   = (const int*)d_in[3];
  const int*   cih    = (const int*)d_in[5];
  const int*   hcls   = (const int*)d_in[6];
  const int*   cit    = (const int*)d_in[7];
  const int*   tcls   = (const int*)d_in[8];
  const float* remb   = (const float*)d_in[9];
  const float* hw1w   = (const float*)d_in[10];
  const float* hw1b   = (const float*)d_in[11];
  const float* hw2w   = (const float*)d_in[12];
  const float* hw2b   = (const float*)d_in[13];
  const float* h2r_ac = (const float*)d_in[14];
  const float* h2r_ar = (const float*)d_in[15];
  const float* h2r_wh = (const float*)d_in[16];
  const float* h2r_wt = (const float*)d_in[17];
  const float* h2r_hww= (const float*)d_in[18];
  const float* h2r_hwb= (const float*)d_in[19];
  const float* et_ac  = (const float*)d_in[20];
  const float* et_ar  = (const float*)d_in[21];
  const float* et_wh  = (const float*)d_in[22];
  const float* et_wt  = (const float*)d_in[23];
  const float* et_hww = (const float*)d_in[24];
  const float* et_hwb = (const float*)d_in[25];
  const float* gai    = (const float*)d_in[26];
  const float* gaj    = (const float*)d_in[27];
  float* out = (float*)d_out;

  // ---- workspace allocator ----
  char* wsp = (char*)d_ws;
  auto alloc = [&](size_t nbytes) -> void* {
    void* p = (void*)wsp;
    wsp += (nbytes + 255) & ~(size_t)255;
    return p;
  };
  float* ra1h = (float*)alloc(Rr * 4);
  float* ra1e = (float*)alloc(Rr * 4);
  float* dis  = (float*)alloc(Nn * 4);
  int* degi    = (int*)alloc(Nn * 4);
  int* csr_ptr = (int*)alloc((Nn + 1) * 4);
  int* csr_cur = (int*)alloc(Nn * 4);
  int* csr_src = (int*)alloc((size_t)EALLe * 4);
  float* x1  = (float*)alloc((size_t)Nn * 600 * 4);
  float* pm  = (float*)alloc(2 * Nn * 4);
  float* po  = (float*)alloc(2 * Nn * 4);
  float* nv4 = (float*)alloc(2 * Nn * 4);
  // contiguous zero-init region: csum_p, ccur_p, x_class
  float* csum_p = (float*)alloc(2 * Cc * 16 * 4);
  int*   ccur_p = (int*)alloc(2 * Cc * 16 * 4);
  float* x_class = (float*)alloc(2 * Cc * CHd * 4);
  size_t zregion = (size_t)((char*)x_class + ((2 * Cc * CHd * 4 + 255) & ~255)) - (size_t)(char*)csum_p;
  int*   crows  = (int*)alloc((size_t)2 * Cc * CAP * 4);
  float* cw     = (float*)alloc((size_t)2 * Cc * CAP * 4);
  float* s1v = (float*)alloc(Nn * 4);
  float* s2v = (float*)alloc(Nn * 4);
  unsigned short* arenaA = (unsigned short*)alloc((size_t)Nn * 320 * 2);
  unsigned short* arenaB = (unsigned short*)alloc((size_t)Nn * 320 * 2);
  unsigned short* x1b    = (unsigned short*)alloc(((size_t)Nn * 600 + 64) * 2);
  unsigned short* w1b    = (unsigned short*)alloc((size_t)300 * 320 * 2);
  unsigned short* w2b    = (unsigned short*)alloc((size_t)300 * 320 * 2);
  unsigned short* wcatb  = (unsigned short*)alloc((size_t)600 * 320 * 2);
  unsigned short* hwwbA  = (unsigned short*)alloc((size_t)150 * 160 * 2);
  unsigned short* hwwbB  = (unsigned short*)alloc((size_t)150 * 160 * 2);
  unsigned short* xob = arenaA;   // 2 x Nn x 160 bf16 (alias, live after arenas die)
  unsigned short* xnb = arenaB;   // 2 x Nn x 152 bf16

  // d_out staging layout (all dead before k_gat4 rewrites d_out)
  float* h1   = out;
  float* gbuf = out + (size_t)Nn * EHd;
  float* proj = out;
  float* outb = out + (size_t)Nn * 600;

  // ---- prologue ----
  hipMemsetAsync(degi, 0, Nn * 4, stream);
  hipMemsetAsync(csum_p, 0, zregion, stream);
  hipMemsetAsync(outb, 0, (size_t)2 * Nn * CHd * 4, stream);
  k_rnorm<<<Rr, 64, 0, stream>>>(remb, h2r_ar, et_ar, ra1h, ra1e);
  k_count<<<cdiv_h(EALLe, 256), 256, 0, stream>>>(eall + EALLe, degi);
  k_scan<<<1, 1024, 0, stream>>>(degi, csr_ptr, csr_cur, dis);
  k_scatter<<<cdiv_h(EALLe, 256), 256, 0, stream>>>(eall, eall + EALLe, csr_cur, csr_src);
  {
    Cvt8 cv;
    cv.s[0] = hw1w;    cv.d[0] = w1b;                         cv.nc[0] = 300; cv.lds[0] = 300; cv.ldp[0] = 320;
    cv.s[1] = hw2w;    cv.d[1] = w2b;                         cv.nc[1] = 300; cv.lds[1] = 300; cv.ldp[1] = 320;
    cv.s[2] = h2r_wh;  cv.d[2] = wcatb + (size_t)0   * 320;   cv.nc[2] = 300; cv.lds[2] = 300; cv.ldp[2] = 320;
    cv.s[3] = h2r_wt;  cv.d[3] = wcatb + (size_t)150 * 320;   cv.nc[3] = 300; cv.lds[3] = 300; cv.ldp[3] = 320;
    cv.s[4] = et_wh;   cv.d[4] = wcatb + (size_t)300 * 320;   cv.nc[4] = 300; cv.lds[4] = 300; cv.ldp[4] = 320;
    cv.s[5] = et_wt;   cv.d[5] = wcatb + (size_t)450 * 320;   cv.nc[5] = 300; cv.lds[5] = 300; cv.ldp[5] = 320;
    cv.s[6] = h2r_hww; cv.d[6] = hwwbA;                       cv.nc[6] = 150; cv.lds[6] = 150; cv.ldp[6] = 160;
    cv.s[7] = et_hww;  cv.d[7] = hwwbB;                       cv.nc[7] = 150; cv.lds[7] = 150; cv.ldp[7] = 160;
    cv.r0[0] = 0;    cv.r0[1] = 300;  cv.r0[2] = 600;  cv.r0[3] = 750;
    cv.r0[4] = 900;  cv.r0[5] = 1050; cv.r0[6] = 1200; cv.r0[7] = 1350; cv.r0[8] = 1500;
    k_f2ball<<<1500, 64, 0, stream>>>(cv);
  }
  k_f2b<<<Nn, 64, 0, stream>>>(x_e, 300, 300, arenaA, 320);

  // ---- GCN + highway x2 ----
  k_gcn4<<<Nn, 256, 0, stream>>>(arenaA, csr_ptr, csr_src, dis, gbuf);
  k_gemmb<1,1><<<dim3(5, cdiv_h(Nn, 64)), 256, 0, stream>>>(
      arenaA, 320, Nn, w1b, 320, 300, hw1b, gbuf, 300, x_e, 300, h1, 300, arenaB, 320);
  k_gcn4<<<Nn, 256, 0, stream>>>(arenaB, csr_ptr, csr_src, dis, gbuf);
  k_gemmb<1,1><<<dim3(5, cdiv_h(Nn, 64)), 256, 0, stream>>>(
      arenaB, 320, Nn, w2b, 320, 300, hw2b, gbuf, 300, h1, 300, x1, 600, x1b, 600);

  // ---- batched projections ----
  k_gemmb<0,0><<<dim3(10, cdiv_h(Nn, 64)), 256, 0, stream>>>(
      x1b, 600, Nn, wcatb, 320, 600, nullptr, nullptr, 0, nullptr, 0, proj, 600,
      nullptr, 0);

  // ---- gat_e: both calls batched per kernel ----
  k_ndots2b<<<dim3(Nn, 2), 64, 0, stream>>>(proj, h2r_ac, et_ac, xob, xnb, pm, po, nv4);
  k_edgescatter<<<dim3(CB, 2), 256, 0, stream>>>(ei, rel, cih, cit, pm, po, ra1h, ra1e,
                                                 csum_p, ccur_p, crows, cw);
  k_xclassBb<<<dim3(Cc * XSPL, 2), 192, 0, stream>>>(ccur_p, crows, cw, csum_p,
                                                     xnb, x_class);
  k_cfinal<<<2, 256, 0, stream>>>(x_class, h2r_ac, et_ac, nv4, hcls, tcls, outb);
  k_hwgemm<<<dim3(3, cdiv_h(Nn, 64), 2), 256, 0, stream>>>(
      xob, hwwbA, hwwbB, h2r_hwb, et_hwb, outb, proj, x1, x1b);

  // ---- final GAT ----
  k_s12<<<Nn, 64, 0, stream>>>(x1b, gai, gaj, s1v, s2v);
  k_gat4<<<Nn, 256, 0, stream>>>(x1, x1b, csr_ptr, csr_src, s1v, s2v, out);
}

// Round 18
// 469.001 us; speedup vs baseline: 1.0926x; 1.0926x over previous
//
#include <hip/hip_runtime.h>
#include <math.h>

#define Nn 20000
#define Ee 120000
#define EALLe 240000
#define Cc 150
#define Rr 1000
#define EHd 300
#define RHd 100
#define CHd 150
#define CB 128
#define XSPL 16
#define CAP 1600

static inline int cdiv_h(int a, int b){ return (a + b - 1) / b; }

typedef __attribute__((ext_vector_type(8))) short short8;
typedef __attribute__((ext_vector_type(4))) float f32x4;

__device__ __forceinline__ float lrelu01(float x){ return x > 0.f ? x : 0.01f * x; }

__device__ __forceinline__ unsigned short f2b(float f){
  unsigned int u = __float_as_uint(f);
  unsigned int r = (u + 0x7FFFu + ((u >> 16) & 1u)) >> 16;
  return (unsigned short)r;
}
__device__ __forceinline__ float b2f(unsigned short u){
  return __uint_as_float(((unsigned int)u) << 16);
}
__device__ __forceinline__ float b2f_lo(unsigned int u){
  return __uint_as_float(u << 16);
}
__device__ __forceinline__ float b2f_hi(unsigned int u){
  return __uint_as_float(u & 0xFFFF0000u);
}

template<int Kq>
__device__ __forceinline__ void wredsumN(float* v){
#pragma unroll
  for (int m = 32; m >= 1; m >>= 1){
#pragma unroll
    for (int k = 0; k < Kq; k++) v[k] += __shfl_xor(v[k], m, 64);
  }
}

__global__ __launch_bounds__(64) void k_f2b(const float* __restrict__ src, int ncols,
    int ldsrc, unsigned short* __restrict__ dst, int ldp){
  int r = blockIdx.x, t = threadIdx.x;
  for (int c = t; c < ldp; c += 64)
    dst[(size_t)r * ldp + c] = (c < ncols) ? f2b(src[(size_t)r * ldsrc + c]) : (unsigned short)0;
}

struct Cvt8 {
  const float* s[8];
  unsigned short* d[8];
  int nc[8]; int lds[8]; int ldp[8]; int r0[9];
};
__global__ __launch_bounds__(64) void k_f2ball(Cvt8 c){
  int b = blockIdx.x, t = threadIdx.x;
  int idx = 0;
#pragma unroll
  for (int q = 1; q < 8; q++) if (b >= c.r0[q]) idx = q;
  int r = b - c.r0[idx];
  const float* src = c.s[idx] + (size_t)r * c.lds[idx];
  unsigned short* dst = c.d[idx] + (size_t)r * c.ldp[idx];
  int nc = c.nc[idx], ldp = c.ldp[idx];
  for (int col = t; col < ldp; col += 64)
    dst[col] = (col < nc) ? f2b(src[col]) : (unsigned short)0;
}

__global__ __launch_bounds__(64) void k_rnorm(const float* __restrict__ rt,
    const float* __restrict__ arh, const float* __restrict__ are,
    float* __restrict__ ra1h, float* __restrict__ ra1e){
  int r = blockIdx.x, lane = threadIdx.x;
  bool m1 = (lane + 64 < RHd);
  float v0 = rt[r * RHd + lane];
  float v1 = m1 ? rt[r * RHd + lane + 64] : 0.f;
  float s[3];
  s[0] = v0 * v0 + v1 * v1;
  s[1] = v0 * arh[RHd + lane] + (m1 ? v1 * arh[RHd + lane + 64] : 0.f);
  s[2] = v0 * are[RHd + lane] + (m1 ? v1 * are[RHd + lane + 64] : 0.f);
  wredsumN<3>(s);
  float inv = 0.5f / fmaxf(sqrtf(s[0]), 1e-12f);
  if (!lane){
    ra1h[r] = s[1] * inv;
    ra1e[r] = s[2] * inv;
  }
}

__global__ void k_count(const int* __restrict__ dst, int* __restrict__ degi){
  int e = blockIdx.x * blockDim.x + threadIdx.x;
  if (e < EALLe) atomicAdd(&degi[dst[e]], 1);
}

__global__ __launch_bounds__(1024) void k_scan(const int* __restrict__ degi,
    int* __restrict__ ptr, int* __restrict__ cur, float* __restrict__ dis){
  __shared__ int s[1024];
  int t = threadIdx.x;
  const int per = (Nn + 1023) / 1024;
  int b0 = t * per; if (b0 > Nn) b0 = Nn;
  int b1 = b0 + per; if (b1 > Nn) b1 = Nn;
  int sum = 0;
  for (int i = b0; i < b1; i++) sum += degi[i];
  s[t] = sum;
  __syncthreads();
  for (int off = 1; off < 1024; off <<= 1){
    int v = (t >= off) ? s[t - off] : 0;
    __syncthreads();
    s[t] += v;
    __syncthreads();
  }
  int run = (t > 0) ? s[t - 1] : 0;
  for (int i = b0; i < b1; i++){
    int dg = degi[i];
    ptr[i] = run; cur[i] = run; run += dg;
    dis[i] = dg > 0 ? rsqrtf((float)dg) : 0.f;
  }
  if (t == 1023) ptr[Nn] = s[1023];
}

__global__ void k_scatter(const int* __restrict__ src, const int* __restrict__ dst,
    int* __restrict__ cur, int* __restrict__ csr_src){
  int e = blockIdx.x * blockDim.x + threadIdx.x;
  if (e >= EALLe) return;
  int pos = atomicAdd(&cur[dst[e]], 1);
  csr_src[pos] = src[e];
}

// GCN SpMM + relu, float4 gathers, 2-deep unroll for ILP
__global__ __launch_bounds__(256) void k_gcn4(const unsigned short* __restrict__ x,
    const int* __restrict__ ptr, const int* __restrict__ src,
    const float* __restrict__ dis, float* __restrict__ out){
  __shared__ float wl[128];
  __shared__ int jl[128];
  __shared__ float red[5][40][8];
  int i = blockIdx.x, t = threadIdx.x;
  int p0 = ptr[i], p1 = ptr[i + 1];
  float* orow = out + (size_t)i * 300;
  if (p0 == p1){
    for (int f = t; f < 300; f += 256) orow[f] = 0.f;
    return;
  }
  int g = t / 40, c = t - g * 40;
  bool act = t < 240;
  float di = dis[i];
  float acc[8] = {};
  for (int base = p0; base < p1; base += 128){
    int k = base + t;
    if (t < 128 && k < p1){
      int j = src[k];
      jl[t] = j;
      wl[t] = di * dis[j];
    }
    __syncthreads();
    int lim = p1 - base; if (lim > 128) lim = 128;
    if (act){
      int q = g;
      for (; q + 6 < lim; q += 12){
        float w0 = wl[q], w1 = wl[q + 6];
        const unsigned short* x0 = x + (size_t)jl[q] * 320;
        const unsigned short* x1p = x + (size_t)jl[q + 6] * 320;
        union { f32x4 f; unsigned int u[4]; } U0, U1;
        U0.f = *(const f32x4*)&x0[8 * c];
        U1.f = *(const f32x4*)&x1p[8 * c];
#pragma unroll
        for (int h = 0; h < 4; h++){
          acc[2 * h]     += w0 * b2f_lo(U0.u[h]) + w1 * b2f_lo(U1.u[h]);
          acc[2 * h + 1] += w0 * b2f_hi(U0.u[h]) + w1 * b2f_hi(U1.u[h]);
        }
      }
      for (; q < lim; q += 6){
        float w = wl[q];
        const unsigned short* xr = x + (size_t)jl[q] * 320;
        union { f32x4 f; unsigned int u[4]; } U;
        U.f = *(const f32x4*)&xr[8 * c];
#pragma unroll
        for (int h = 0; h < 4; h++){
          acc[2 * h]     += w * b2f_lo(U.u[h]);
          acc[2 * h + 1] += w * b2f_hi(U.u[h]);
        }
      }
    }
    __syncthreads();
  }
  if (act && g > 0){
#pragma unroll
    for (int h = 0; h < 8; h++) red[g - 1][c][h] = acc[h];
  }
  __syncthreads();
  if (g == 0){
#pragma unroll
    for (int h = 0; h < 8; h++){
      float v = acc[h];
#pragma unroll
      for (int r = 0; r < 5; r++) v += red[r][c][h];
      acc[h] = fmaxf(v, 0.f);
    }
    int col0 = 8 * c;
    if (col0 + 8 <= 300){
      f32x4 o0 = { acc[0], acc[1], acc[2], acc[3] };
      f32x4 o1 = { acc[4], acc[5], acc[6], acc[7] };
      *(f32x4*)&orow[col0] = o0;
      *(f32x4*)&orow[col0 + 4] = o1;
    } else {
      for (int h = 0; h < 8 && col0 + h < 300; h++) orow[col0 + h] = acc[h];
    }
  }
}

// final GAT: fused x-copy + in-LDS edge weights + float4 gathers, 2-deep unroll
__global__ __launch_bounds__(256) void k_gat4(const float* __restrict__ x1,
    const unsigned short* __restrict__ x1b,
    const int* __restrict__ ptr, const int* __restrict__ src,
    const float* __restrict__ s1, const float* __restrict__ s2,
    float* __restrict__ dout){
  __shared__ float wl[128];
  __shared__ int jl[128];
  __shared__ float red[2][75][8];
  int i = blockIdx.x, t = threadIdx.x;
  float* orow = dout + (size_t)i * 900;
  const float* xi = x1 + (size_t)i * 600;
  if (t < 75) ((f32x4*)orow)[t] = ((const f32x4*)xi)[t];
  int p0 = ptr[i], p1 = ptr[i + 1];
  if (p0 == p1){
    for (int f = t; f < 600; f += 256) orow[300 + f] = 0.f;
    return;
  }
  float s1i = s1[i];
  int g = t / 75, c = t - g * 75;
  bool act = t < 225;
  float acc[8] = {};
  float den = 0.f;
  for (int base = p0; base < p1; base += 128){
    int k = base + t;
    if (t < 128 && k < p1){
      int j = src[k];
      jl[t] = j;
      wl[t] = expf(lrelu01(s1i + s2[j]));
    }
    __syncthreads();
    int lim = p1 - base; if (lim > 128) lim = 128;
    for (int q = 0; q < lim; q++) den += wl[q];
    if (act){
      int q = g;
      for (; q + 3 < lim; q += 6){
        float w0 = wl[q], w1 = wl[q + 3];
        const unsigned short* x0 = x1b + (size_t)jl[q] * 600;
        const unsigned short* x1p = x1b + (size_t)jl[q + 3] * 600;
        union { f32x4 f; unsigned int u[4]; } U0, U1;
        U0.f = *(const f32x4*)&x0[8 * c];
        U1.f = *(const f32x4*)&x1p[8 * c];
#pragma unroll
        for (int h = 0; h < 4; h++){
          acc[2 * h]     += w0 * b2f_lo(U0.u[h]) + w1 * b2f_lo(U1.u[h]);
          acc[2 * h + 1] += w0 * b2f_hi(U0.u[h]) + w1 * b2f_hi(U1.u[h]);
        }
      }
      for (; q < lim; q += 3){
        float w = wl[q];
        const unsigned short* xj = x1b + (size_t)jl[q] * 600;
        union { f32x4 f; unsigned int u[4]; } U;
        U.f = *(const f32x4*)&xj[8 * c];
#pragma unroll
        for (int h = 0; h < 4; h++){
          acc[2 * h]     += w * b2f_lo(U.u[h]);
          acc[2 * h + 1] += w * b2f_hi(U.u[h]);
        }
      }
    }
    __syncthreads();
  }
  if (act && g > 0){
#pragma unroll
    for (int h = 0; h < 8; h++) red[g - 1][c][h] = acc[h];
  }
  __syncthreads();
  if (g == 0){
    float invd = 1.f / den;
#pragma unroll
    for (int h = 0; h < 8; h++){
      float v = acc[h] + red[0][c][h] + red[1][c][h];
      acc[h] = fmaxf(v * invd, 0.f);
    }
    f32x4 o0 = { acc[0], acc[1], acc[2], acc[3] };
    f32x4 o1 = { acc[4], acc[5], acc[6], acc[7] };
    ((f32x4*)(orow + 300))[2 * c] = o0;
    ((f32x4*)(orow + 300))[2 * c + 1] = o1;
  }
}

// bf16 MFMA GEMM
template<int EPI, int MIR>
__global__ __launch_bounds__(256) void k_gemmb(
    const unsigned short* __restrict__ Xb, int ldxb, int nrows,
    const unsigned short* __restrict__ Wb, int Kp, int M,
    const float* __restrict__ bias,
    const float* __restrict__ X2, int ldx2,
    const float* __restrict__ Xf, int ldxf,
    float* __restrict__ out, int ldo,
    unsigned short* __restrict__ mir, int ldmir){
  __shared__ unsigned short Xs[64][40];
  __shared__ unsigned short Ws[64][40];
  int t = threadIdx.x;
  int wv = t >> 6, lane = t & 63;
  int c0 = blockIdx.x * 64, r0 = blockIdx.y * 64;
  int srow = t >> 2, skoff = (t & 3) * 8;
  int gxr = r0 + srow, gwr = c0 + srow;
  f32x4 acc[4] = {};
  for (int k0 = 0; k0 < Kp; k0 += 32){
    short8 xv = {0,0,0,0,0,0,0,0};
    short8 wv8 = {0,0,0,0,0,0,0,0};
    if (gxr < nrows) xv = *(const short8*)&Xb[(size_t)gxr * ldxb + k0 + skoff];
    if (gwr < M)     wv8 = *(const short8*)&Wb[(size_t)gwr * Kp + k0 + skoff];
    __syncthreads();
    *(short8*)&Xs[srow][skoff] = xv;
    *(short8*)&Ws[srow][skoff] = wv8;
    __syncthreads();
    int arow = wv * 16 + (lane & 15);
    int kk = (lane >> 4) * 8;
    short8 af = *(const short8*)&Xs[arow][kk];
#pragma unroll
    for (int j = 0; j < 4; j++){
      short8 bf = *(const short8*)&Ws[j * 16 + (lane & 15)][kk];
      acc[j] = __builtin_amdgcn_mfma_f32_16x16x32_bf16(af, bf, acc[j], 0, 0, 0);
    }
  }
  int rbase = r0 + wv * 16 + (lane >> 4) * 4;
  int cbase = c0 + (lane & 15);
#pragma unroll
  for (int j = 0; j < 4; j++){
    int c = cbase + j * 16;
    if (c >= M) continue;
#pragma unroll
    for (int r = 0; r < 4; r++){
      int row = rbase + r;
      if (row >= nrows) continue;
      float v = acc[j][r];
      float o;
      if (EPI == 0){
        o = fmaxf(v, 0.f);
      } else {
        float g = 1.f / (1.f + expf(-(v + bias[c])));
        o = g * X2[(size_t)row * ldx2 + c] + (1.f - g) * Xf[(size_t)row * ldxf + c];
      }
      out[(size_t)row * ldo + c] = o;
      if (MIR) mir[(size_t)row * ldmir + c] = f2b(o);
    }
  }
}

// batched gat_e highway GEMM
__global__ __launch_bounds__(256) void k_hwgemm(
    const unsigned short* __restrict__ xob,
    const unsigned short* __restrict__ hwwbA, const unsigned short* __restrict__ hwwbB,
    const float* __restrict__ hwbA, const float* __restrict__ hwbB,
    const float* __restrict__ outb, const float* __restrict__ proj,
    float* __restrict__ x1, unsigned short* __restrict__ x1b){
  __shared__ unsigned short Xs[64][40];
  __shared__ unsigned short Ws[64][40];
  int g = blockIdx.z;
  const unsigned short* Xb = xob + (size_t)g * Nn * 160;
  const unsigned short* Wb = g ? hwwbB : hwwbA;
  const float* bias = g ? hwbB : hwbA;
  const float* X2 = outb + (size_t)g * Nn * CHd;
  const float* Xf = proj + (g ? 450 : 0);
  float* outp = x1 + (g ? 450 : 300);
  unsigned short* mir = x1b + (g ? 450 : 300);
  int t = threadIdx.x;
  int wv = t >> 6, lane = t & 63;
  int c0 = blockIdx.x * 64, r0 = blockIdx.y * 64;
  int srow = t >> 2, skoff = (t & 3) * 8;
  int gxr = r0 + srow, gwr = c0 + srow;
  f32x4 acc[4] = {};
  for (int k0 = 0; k0 < 160; k0 += 32){
    short8 xv = {0,0,0,0,0,0,0,0};
    short8 wv8 = {0,0,0,0,0,0,0,0};
    if (gxr < Nn) xv = *(const short8*)&Xb[(size_t)gxr * 160 + k0 + skoff];
    if (gwr < 150) wv8 = *(const short8*)&Wb[(size_t)gwr * 160 + k0 + skoff];
    __syncthreads();
    *(short8*)&Xs[srow][skoff] = xv;
    *(short8*)&Ws[srow][skoff] = wv8;
    __syncthreads();
    int arow = wv * 16 + (lane & 15);
    int kk = (lane >> 4) * 8;
    short8 af = *(const short8*)&Xs[arow][kk];
#pragma unroll
    for (int j = 0; j < 4; j++){
      short8 bf = *(const short8*)&Ws[j * 16 + (lane & 15)][kk];
      acc[j] = __builtin_amdgcn_mfma_f32_16x16x32_bf16(af, bf, acc[j], 0, 0, 0);
    }
  }
  int rbase = r0 + wv * 16 + (lane >> 4) * 4;
  int cbase = c0 + (lane & 15);
#pragma unroll
  for (int j = 0; j < 4; j++){
    int c = cbase + j * 16;
    if (c >= 150) continue;
#pragma unroll
    for (int r = 0; r < 4; r++){
      int row = rbase + r;
      if (row >= Nn) continue;
      float v = acc[j][r];
      float gg = 1.f / (1.f + expf(-(v + bias[c])));
      float o = gg * X2[(size_t)row * CHd + c] + (1.f - gg) * Xf[(size_t)row * 600 + c];
      outp[(size_t)row * 600 + c] = o;
      mir[(size_t)row * 600 + c] = f2b(o);
    }
  }
}

// batched per-node precompute for both gat_e calls + fused xo->bf16 mirror
__global__ __launch_bounds__(64) void k_ndots2b(const float* __restrict__ proj,
    const float* __restrict__ h2r_ac, const float* __restrict__ et_ac,
    unsigned short* __restrict__ xob,
    unsigned short* __restrict__ xnb, float* __restrict__ pm,
    float* __restrict__ po, float* __restrict__ nv4){
  int n = blockIdx.x, g = blockIdx.y, lane = threadIdx.x;
  const float* ac = g ? et_ac : h2r_ac;
  const float* xm = proj + (g ? 300 : 150);
  const float* xo = proj + (g ? 450 : 0);
  const float* v2m = ac + (g ? 1 : 5) * CHd;
  const float* v2o = ac + (g ? 5 : 1) * CHd;
  const float* v3m = ac + (g ? 2 : 6) * CHd;
  const float* v3o = ac + (g ? 6 : 2) * CHd;
  const float* v4  = ac + 3 * CHd;
  bool m2 = lane < (CHd - 128);
  const float* mr = xm + (size_t)n * 600;
  const float* orw = xo + (size_t)n * 600;
  float m0 = mr[lane], m1 = mr[lane + 64], mv2 = m2 ? mr[lane + 128] : 0.f;
  float o0 = orw[lane], o1 = orw[lane + 64], o2 = m2 ? orw[lane + 128] : 0.f;
  unsigned short* xod = xob + (size_t)g * Nn * 160 + (size_t)n * 160;
  xod[lane] = f2b(o0);
  xod[lane + 64] = f2b(o1);
  if (m2) xod[lane + 128] = f2b(o2);
  if (lane < 10) xod[150 + lane] = 0;
  float s[4];
  s[0] = m0 * m0 + m1 * m1 + mv2 * mv2;
  s[1] = o0 * v2o[lane] + o1 * v2o[lane + 64] + (m2 ? o2 * v2o[lane + 128] : 0.f);
  s[2] = o0 * v3o[lane] + o1 * v3o[lane + 64] + (m2 ? o2 * v3o[lane + 128] : 0.f);
  s[3] = o0 * v4[lane]  + o1 * v4[lane + 64]  + (m2 ? o2 * v4[lane + 128]  : 0.f);
  wredsumN<4>(s);
  float inv = 1.f / fmaxf(sqrtf(s[0]), 1e-12f);
  float n0 = m0 * inv, n1 = m1 * inv, n2 = mv2 * inv;
  unsigned short* xr = xnb + (size_t)g * Nn * 152 + (size_t)n * 152;
  xr[lane] = f2b(n0); xr[lane + 64] = f2b(n1);
  if (m2) xr[lane + 128] = f2b(n2);
  float d[2];
  d[0] = n0 * v2m[lane] + n1 * v2m[lane + 64] + (m2 ? n2 * v2m[lane + 128] : 0.f);
  d[1] = n0 * v3m[lane] + n1 * v3m[lane + 64] + (m2 ? n2 * v3m[lane + 128] : 0.f);
  wredsumN<2>(d);
  if (!lane){
    pm[g * Nn + n] = d[0] + 0.25f * d[1];
    po[g * Nn + n] = s[1] + 0.25f * s[2];
    nv4[g * Nn + n] = s[3];
  }
}

// SINGLE-PASS edge kernel: exp-logit + class sums + direct class-bucket scatter.
__global__ __launch_bounds__(256) void k_edgescatter(const int* __restrict__ ei,
    const int* __restrict__ rel, const int* __restrict__ cih, const int* __restrict__ cit,
    const float* __restrict__ pm, const float* __restrict__ po,
    const float* __restrict__ ra1h, const float* __restrict__ ra1e,
    float* __restrict__ csum_p, int* __restrict__ ccur_p,
    int* __restrict__ crows, float* __restrict__ cw){
  __shared__ float ls[Cc];
  __shared__ int lcnt[Cc];
  __shared__ int lbase[Cc];
  int t = threadIdx.x, g = blockIdx.y;
  const int* im = ei + (g ? 0 : Ee);
  const int* io = ei + (g ? Ee : 0);
  const int* ci = g ? cit : cih;
  const float* ra1 = g ? ra1e : ra1h;
  const float* pmg = pm + g * Nn;
  const float* pog = po + g * Nn;
  float* csg = csum_p + g * Cc * 16;
  int* cug = ccur_p + g * Cc * 16;
  int* crg = crows + (size_t)g * Cc * CAP;
  float* cwg = cw + (size_t)g * Cc * CAP;
  int epb = (Ee + gridDim.x - 1) / gridDim.x;
  int e0 = blockIdx.x * epb, e1 = e0 + epb; if (e1 > Ee) e1 = Ee;
  for (int c = t; c < Cc; c += 256){ ls[c] = 0.f; lcnt[c] = 0; }
  __syncthreads();
  int myr[4], myc[4], myrow[4]; float myw[4]; int cnt = 0;
  for (int e = e0 + t; e < e1; e += 256){
    float v = lrelu01(pog[io[e]] + pmg[im[e]] + ra1[rel[e]]);
    float s = expf(v);
    int c = ci[e];
    atomicAdd(&ls[c], s);
    myr[cnt] = atomicAdd(&lcnt[c], 1);
    myc[cnt] = c; myw[cnt] = s; myrow[cnt] = im[im[e]];
    cnt++;
  }
  __syncthreads();
  for (int c = t; c < Cc; c += 256){
    if (lcnt[c]){
      lbase[c] = atomicAdd(&cug[c * 16], lcnt[c]);
      atomicAdd(&csg[c * 16], ls[c]);
    }
  }
  __syncthreads();
  for (int q = 0; q < cnt; q++){
    int c = myc[q];
    int pos = c * CAP + lbase[c] + myr[q];
    crg[pos] = myrow[q];
    cwg[pos] = myw[q];
  }
}

// class x_class accumulation: XSPL blocks per class; range = [c*CAP, c*CAP+len)
__global__ __launch_bounds__(192) void k_xclassBb(
    const int* __restrict__ ccur_p, const int* __restrict__ crows,
    const float* __restrict__ cw, const float* __restrict__ csum_p,
    const unsigned short* __restrict__ xnb, float* __restrict__ x_class){
  int g = blockIdx.y;
  int c = blockIdx.x / XSPL, sp = blockIdx.x % XSPL;
  int t = threadIdx.x;
  const int* crg = crows + (size_t)g * Cc * CAP;
  const float* cwg = cw + (size_t)g * Cc * CAP;
  const unsigned short* xng = xnb + (size_t)g * Nn * 152;
  float* xcg = x_class + g * Cc * CHd;
  int len = ccur_p[g * Cc * 16 + c * 16];
  if (len <= 0) return;
  int chunk = (len + XSPL - 1) / XSPL;
  int q0 = c * CAP + sp * chunk;
  int q1 = q0 + chunk;
  int qend = c * CAP + len;
  if (q1 > qend) q1 = qend;
  if (q0 >= q1) return;
  bool act = t < CHd;
  float inv = 1.f / csum_p[g * Cc * 16 + c * 16];
  float acc = 0.f;
  int k = q0;
  for (; k + 4 <= q1; k += 4){
    int r0 = crg[k], r1 = crg[k + 1], r2 = crg[k + 2], r3 = crg[k + 3];
    float w0 = cwg[k] * inv, w1 = cwg[k + 1] * inv, w2 = cwg[k + 2] * inv, w3 = cwg[k + 3] * inv;
    if (act){
      acc += w0 * b2f(xng[(size_t)r0 * 152 + t]) + w1 * b2f(xng[(size_t)r1 * 152 + t])
           + w2 * b2f(xng[(size_t)r2 * 152 + t]) + w3 * b2f(xng[(size_t)r3 * 152 + t]);
    }
  }
  for (; k < q1; k++){
    if (act) acc += cwg[k] * inv * b2f(xng[(size_t)crg[k] * 152 + t]);
  }
  if (act) atomicAdd(&xcg[c * CHd + t], acc);
}

// class-final step 1: one wave per (class, call): vv = lrelu(x_class[c].acv + nv4[ce[c]])
__global__ __launch_bounds__(64) void k_ecb(const float* __restrict__ x_class,
    const float* __restrict__ h2r_ac, const float* __restrict__ et_ac,
    const float* __restrict__ nv4,
    const int* __restrict__ hcls, const int* __restrict__ tcls,
    float* __restrict__ vv){
  int c = blockIdx.x, g = blockIdx.y, lane = threadIdx.x;
  const float* xc = x_class + (size_t)g * Cc * CHd + (size_t)c * CHd;
  const float* acv = (g ? et_ac : h2r_ac) + 7 * CHd;
  bool m2 = lane < (CHd - 128);
  float s[1];
  s[0] = xc[lane] * acv[lane] + xc[lane + 64] * acv[lane + 64]
       + (m2 ? xc[lane + 128] * acv[lane + 128] : 0.f);
  wredsumN<1>(s);
  if (!lane){
    int ce = (g ? tcls : hcls)[c];
    vv[g * Cc + c] = lrelu01(s[0] + nv4[g * Nn + ce]);
  }
}

// class-final step 2: per call g, segment softmax over cls_ent -> gmv
__global__ __launch_bounds__(256) void k_gammab(const float* __restrict__ vv,
    const int* __restrict__ hcls, const int* __restrict__ tcls,
    float* __restrict__ gmv){
  __shared__ float v[Cc];
  __shared__ int ce[Cc];
  int t = threadIdx.x, g = blockIdx.x;
  const int* cls_ent = g ? tcls : hcls;
  if (t < Cc){
    v[t] = vv[g * Cc + t];
    ce[t] = cls_ent[t];
  }
  __syncthreads();
  if (t < Cc){
    int sgm = ce[t];
    float m = -3.0e38f;
    for (int c2 = 0; c2 < Cc; c2++) if (ce[c2] == sgm) m = fmaxf(m, v[c2]);
    float sum = 0.f;
    for (int c2 = 0; c2 < Cc; c2++) if (ce[c2] == sgm) sum += expf(v[c2] - m);
    gmv[g * Cc + t] = expf(v[t] - m) / sum;
  }
}

// class-final step 3: parallel scatter outb[ce[c]] += gm[c] * x_class[c]
__global__ __launch_bounds__(256) void k_cfscatter(const float* __restrict__ x_class,
    const float* __restrict__ gmv,
    const int* __restrict__ hcls, const int* __restrict__ tcls,
    float* __restrict__ outb){
  int g = blockIdx.y;
  int idx = blockIdx.x * 256 + threadIdx.x;
  if (idx >= Cc * CHd) return;
  int c = idx / CHd, f = idx - c * CHd;
  int ce = (g ? tcls : hcls)[c];
  float val = gmv[g * Cc + c] * x_class[(size_t)g * Cc * CHd + idx];
  atomicAdd(&outb[(size_t)g * Nn * CHd + (size_t)ce * CHd + f], val);
}

// per node dot of x1b row with gat_ai / gat_aj — dword loads
__global__ __launch_bounds__(64) void k_s12(const unsigned short* __restrict__ x1b,
    const float* __restrict__ ai, const float* __restrict__ aj,
    float* __restrict__ s1, float* __restrict__ s2){
  int n = blockIdx.x, lane = threadIdx.x;
  const unsigned int* xr = (const unsigned int*)(x1b + (size_t)n * 600);
  float sa = 0.f, sb = 0.f;
#pragma unroll
  for (int u = 0; u < 5; u++){
    int d = lane + u * 64;
    if (d < 300){
      unsigned int w = xr[d];
      float xlo = b2f_lo(w), xhi = b2f_hi(w);
      sa += xlo * ai[2 * d] + xhi * ai[2 * d + 1];
      sb += xlo * aj[2 * d] + xhi * aj[2 * d + 1];
    }
  }
  float s[2] = { sa, sb };
  wredsumN<2>(s);
  if (!lane){ s1[n] = s[0]; s2[n] = s[1]; }
}

extern "C" void kernel_launch(void* const* d_in, const int* in_sizes, int n_in,
                              void* d_out, int out_size, void* d_ws, size_t ws_size,
                              hipStream_t stream) {
  const float* x_e    = (const float*)d_in[0];
  const int*   ei     = (const int*)d_in[1];
  const int*   rel    = (const int*)d_in[2];
  const int*   eall   = (const int*)d_in[3];
  const int*   cih    = (const int*)d_in[5];
  const int*   hcls   = (const int*)d_in[6];
  const int*   cit    = (const int*)d_in[7];
  const int*   tcls   = (const int*)d_in[8];
  const float* remb   = (const float*)d_in[9];
  const float* hw1w   = (const float*)d_in[10];
  const float* hw1b   = (const float*)d_in[11];
  const float* hw2w   = (const float*)d_in[12];
  const float* hw2b   = (const float*)d_in[13];
  const float* h2r_ac = (const float*)d_in[14];
  const float* h2r_ar = (const float*)d_in[15];
  const float* h2r_wh = (const float*)d_in[16];
  const float* h2r_wt = (const float*)d_in[17];
  const float* h2r_hww= (const float*)d_in[18];
  const float* h2r_hwb= (const float*)d_in[19];
  const float* et_ac  = (const float*)d_in[20];
  const float* et_ar  = (const float*)d_in[21];
  const float* et_wh  = (const float*)d_in[22];
  const float* et_wt  = (const float*)d_in[23];
  const float* et_hww = (const float*)d_in[24];
  const float* et_hwb = (const float*)d_in[25];
  const float* gai    = (const float*)d_in[26];
  const float* gaj    = (const float*)d_in[27];
  float* out = (float*)d_out;

  // ---- workspace allocator ----
  char* wsp = (char*)d_ws;
  auto alloc = [&](size_t nbytes) -> void* {
    void* p = (void*)wsp;
    wsp += (nbytes + 255) & ~(size_t)255;
    return p;
  };
  float* ra1h = (float*)alloc(Rr * 4);
  float* ra1e = (float*)alloc(Rr * 4);
  float* dis  = (float*)alloc(Nn * 4);
  int* degi    = (int*)alloc(Nn * 4);
  int* csr_ptr = (int*)alloc((Nn + 1) * 4);
  int* csr_cur = (int*)alloc(Nn * 4);
  int* csr_src = (int*)alloc((size_t)EALLe * 4);
  float* x1  = (float*)alloc((size_t)Nn * 600 * 4);
  float* pm  = (float*)alloc(2 * Nn * 4);
  float* po  = (float*)alloc(2 * Nn * 4);
  float* nv4 = (float*)alloc(2 * Nn * 4);
  // contiguous zero-init region: csum_p, ccur_p, x_class
  float* csum_p = (float*)alloc(2 * Cc * 16 * 4);
  int*   ccur_p = (int*)alloc(2 * Cc * 16 * 4);
  float* x_class = (float*)alloc(2 * Cc * CHd * 4);
  size_t zregion = (size_t)((char*)x_class + ((2 * Cc * CHd * 4 + 255) & ~255)) - (size_t)(char*)csum_p;
  int*   crows  = (int*)alloc((size_t)2 * Cc * CAP * 4);
  float* cw     = (float*)alloc((size_t)2 * Cc * CAP * 4);
  float* s1v = (float*)alloc(Nn * 4);
  float* s2v = (float*)alloc(Nn * 4);
  float* vv  = (float*)alloc(2 * Cc * 4);
  float* gmv = (float*)alloc(2 * Cc * 4);
  unsigned short* arenaA = (unsigned short*)alloc((size_t)Nn * 320 * 2);
  unsigned short* arenaB = (unsigned short*)alloc((size_t)Nn * 320 * 2);
  unsigned short* x1b    = (unsigned short*)alloc(((size_t)Nn * 600 + 64) * 2);
  unsigned short* w1b    = (unsigned short*)alloc((size_t)300 * 320 * 2);
  unsigned short* w2b    = (unsigned short*)alloc((size_t)300 * 320 * 2);
  unsigned short* wcatb  = (unsigned short*)alloc((size_t)600 * 320 * 2);
  unsigned short* hwwbA  = (unsigned short*)alloc((size_t)150 * 160 * 2);
  unsigned short* hwwbB  = (unsigned short*)alloc((size_t)150 * 160 * 2);
  unsigned short* xob = arenaA;   // 2 x Nn x 160 bf16 (alias, live after arenas die)
  unsigned short* xnb = arenaB;   // 2 x Nn x 152 bf16

  // d_out staging layout (all dead before k_gat4 rewrites d_out)
  float* h1   = out;
  float* gbuf = out + (size_t)Nn * EHd;
  float* proj = out;
  float* outb = out + (size_t)Nn * 600;

  // ---- prologue ----
  hipMemsetAsync(degi, 0, Nn * 4, stream);
  hipMemsetAsync(csum_p, 0, zregion, stream);
  hipMemsetAsync(outb, 0, (size_t)2 * Nn * CHd * 4, stream);
  k_rnorm<<<Rr, 64, 0, stream>>>(remb, h2r_ar, et_ar, ra1h, ra1e);
  k_count<<<cdiv_h(EALLe, 256), 256, 0, stream>>>(eall + EALLe, degi);
  k_scan<<<1, 1024, 0, stream>>>(degi, csr_ptr, csr_cur, dis);
  k_scatter<<<cdiv_h(EALLe, 256), 256, 0, stream>>>(eall, eall + EALLe, csr_cur, csr_src);
  {
    Cvt8 cv;
    cv.s[0] = hw1w;    cv.d[0] = w1b;                         cv.nc[0] = 300; cv.lds[0] = 300; cv.ldp[0] = 320;
    cv.s[1] = hw2w;    cv.d[1] = w2b;                         cv.nc[1] = 300; cv.lds[1] = 300; cv.ldp[1] = 320;
    cv.s[2] = h2r_wh;  cv.d[2] = wcatb + (size_t)0   * 320;   cv.nc[2] = 300; cv.lds[2] = 300; cv.ldp[2] = 320;
    cv.s[3] = h2r_wt;  cv.d[3] = wcatb + (size_t)150 * 320;   cv.nc[3] = 300; cv.lds[3] = 300; cv.ldp[3] = 320;
    cv.s[4] = et_wh;   cv.d[4] = wcatb + (size_t)300 * 320;   cv.nc[4] = 300; cv.lds[4] = 300; cv.ldp[4] = 320;
    cv.s[5] = et_wt;   cv.d[5] = wcatb + (size_t)450 * 320;   cv.nc[5] = 300; cv.lds[5] = 300; cv.ldp[5] = 320;
    cv.s[6] = h2r_hww; cv.d[6] = hwwbA;                       cv.nc[6] = 150; cv.lds[6] = 150; cv.ldp[6] = 160;
    cv.s[7] = et_hww;  cv.d[7] = hwwbB;                       cv.nc[7] = 150; cv.lds[7] = 150; cv.ldp[7] = 160;
    cv.r0[0] = 0;    cv.r0[1] = 300;  cv.r0[2] = 600;  cv.r0[3] = 750;
    cv.r0[4] = 900;  cv.r0[5] = 1050; cv.r0[6] = 1200; cv.r0[7] = 1350; cv.r0[8] = 1500;
    k_f2ball<<<1500, 64, 0, stream>>>(cv);
  }
  k_f2b<<<Nn, 64, 0, stream>>>(x_e, 300, 300, arenaA, 320);

  // ---- GCN + highway x2 ----
  k_gcn4<<<Nn, 256, 0, stream>>>(arenaA, csr_ptr, csr_src, dis, gbuf);
  k_gemmb<1,1><<<dim3(5, cdiv_h(Nn, 64)), 256, 0, stream>>>(
      arenaA, 320, Nn, w1b, 320, 300, hw1b, gbuf, 300, x_e, 300, h1, 300, arenaB, 320);
  k_gcn4<<<Nn, 256, 0, stream>>>(arenaB, csr_ptr, csr_src, dis, gbuf);
  k_gemmb<1,1><<<dim3(5, cdiv_h(Nn, 64)), 256, 0, stream>>>(
      arenaB, 320, Nn, w2b, 320, 300, hw2b, gbuf, 300, h1, 300, x1, 600, x1b, 600);

  // ---- batched projections ----
  k_gemmb<0,0><<<dim3(10, cdiv_h(Nn, 64)), 256, 0, stream>>>(
      x1b, 600, Nn, wcatb, 320, 600, nullptr, nullptr, 0, nullptr, 0, proj, 600,
      nullptr, 0);

  // ---- gat_e: both calls batched per kernel ----
  k_ndots2b<<<dim3(Nn, 2), 64, 0, stream>>>(proj, h2r_ac, et_ac, xob, xnb, pm, po, nv4);
  k_edgescatter<<<dim3(CB, 2), 256, 0, stream>>>(ei, rel, cih, cit, pm, po, ra1h, ra1e,
                                                 csum_p, ccur_p, crows, cw);
  k_xclassBb<<<dim3(Cc * XSPL, 2), 192, 0, stream>>>(ccur_p, crows, cw, csum_p,
                                                     xnb, x_class);
  // class-final: parallel 3-stage (wave-dot -> segment softmax -> scatter)
  k_ecb<<<dim3(Cc, 2), 64, 0, stream>>>(x_class, h2r_ac, et_ac, nv4, hcls, tcls, vv);
  k_gammab<<<2, 256, 0, stream>>>(vv, hcls, tcls, gmv);
  k_cfscatter<<<dim3(cdiv_h(Cc * CHd, 256), 2), 256, 0, stream>>>(
      x_class, gmv, hcls, tcls, outb);
  k_hwgemm<<<dim3(3, cdiv_h(Nn, 64), 2), 256, 0, stream>>>(
      xob, hwwbA, hwwbB, h2r_hwb, et_hwb, outb, proj, x1, x1b);

  // ---- final GAT ----
  k_s12<<<Nn, 64, 0, stream>>>(x1b, gai, gaj, s1v, s2v);
  k_gat4<<<Nn, 256, 0, stream>>>(x1, x1b, csr_ptr, csr_src, s1v, s2v, out);
}

// Round 19
// 466.052 us; speedup vs baseline: 1.0995x; 1.0063x over previous
//
#include <hip/hip_runtime.h>
#include <math.h>

#define Nn 20000
#define Ee 120000
#define EALLe 240000
#define Cc 150
#define Rr 1000
#define EHd 300
#define RHd 100
#define CHd 150
#define CB 128
#define XSPL 16
#define CAP 1600

static inline int cdiv_h(int a, int b){ return (a + b - 1) / b; }

typedef __attribute__((ext_vector_type(8))) short short8;
typedef __attribute__((ext_vector_type(4))) float f32x4;

__device__ __forceinline__ float lrelu01(float x){ return x > 0.f ? x : 0.01f * x; }

__device__ __forceinline__ unsigned short f2b(float f){
  unsigned int u = __float_as_uint(f);
  unsigned int r = (u + 0x7FFFu + ((u >> 16) & 1u)) >> 16;
  return (unsigned short)r;
}
__device__ __forceinline__ float b2f(unsigned short u){
  return __uint_as_float(((unsigned int)u) << 16);
}
__device__ __forceinline__ float b2f_lo(unsigned int u){
  return __uint_as_float(u << 16);
}
__device__ __forceinline__ float b2f_hi(unsigned int u){
  return __uint_as_float(u & 0xFFFF0000u);
}

template<int Kq>
__device__ __forceinline__ void wredsumN(float* v){
#pragma unroll
  for (int m = 32; m >= 1; m >>= 1){
#pragma unroll
    for (int k = 0; k < Kq; k++) v[k] += __shfl_xor(v[k], m, 64);
  }
}

__global__ __launch_bounds__(64) void k_f2b(const float* __restrict__ src, int ncols,
    int ldsrc, unsigned short* __restrict__ dst, int ldp){
  int r = blockIdx.x, t = threadIdx.x;
  for (int c = t; c < ldp; c += 64)
    dst[(size_t)r * ldp + c] = (c < ncols) ? f2b(src[(size_t)r * ldsrc + c]) : (unsigned short)0;
}

struct Cvt8 {
  const float* s[8];
  unsigned short* d[8];
  int nc[8]; int lds[8]; int ldp[8]; int r0[9];
};
__global__ __launch_bounds__(64) void k_f2ball(Cvt8 c){
  int b = blockIdx.x, t = threadIdx.x;
  int idx = 0;
#pragma unroll
  for (int q = 1; q < 8; q++) if (b >= c.r0[q]) idx = q;
  int r = b - c.r0[idx];
  const float* src = c.s[idx] + (size_t)r * c.lds[idx];
  unsigned short* dst = c.d[idx] + (size_t)r * c.ldp[idx];
  int nc = c.nc[idx], ldp = c.ldp[idx];
  for (int col = t; col < ldp; col += 64)
    dst[col] = (col < nc) ? f2b(src[col]) : (unsigned short)0;
}

__global__ __launch_bounds__(64) void k_rnorm(const float* __restrict__ rt,
    const float* __restrict__ arh, const float* __restrict__ are,
    float* __restrict__ ra1h, float* __restrict__ ra1e){
  int r = blockIdx.x, lane = threadIdx.x;
  bool m1 = (lane + 64 < RHd);
  float v0 = rt[r * RHd + lane];
  float v1 = m1 ? rt[r * RHd + lane + 64] : 0.f;
  float s[3];
  s[0] = v0 * v0 + v1 * v1;
  s[1] = v0 * arh[RHd + lane] + (m1 ? v1 * arh[RHd + lane + 64] : 0.f);
  s[2] = v0 * are[RHd + lane] + (m1 ? v1 * are[RHd + lane + 64] : 0.f);
  wredsumN<3>(s);
  float inv = 0.5f / fmaxf(sqrtf(s[0]), 1e-12f);
  if (!lane){
    ra1h[r] = s[1] * inv;
    ra1e[r] = s[2] * inv;
  }
}

__global__ void k_count(const int* __restrict__ dst, int* __restrict__ degi){
  int e = blockIdx.x * blockDim.x + threadIdx.x;
  if (e < EALLe) atomicAdd(&degi[dst[e]], 1);
}

__global__ __launch_bounds__(1024) void k_scan(const int* __restrict__ degi,
    int* __restrict__ ptr, int* __restrict__ cur, float* __restrict__ dis){
  __shared__ int s[1024];
  int t = threadIdx.x;
  const int per = (Nn + 1023) / 1024;
  int b0 = t * per; if (b0 > Nn) b0 = Nn;
  int b1 = b0 + per; if (b1 > Nn) b1 = Nn;
  int sum = 0;
  for (int i = b0; i < b1; i++) sum += degi[i];
  s[t] = sum;
  __syncthreads();
  for (int off = 1; off < 1024; off <<= 1){
    int v = (t >= off) ? s[t - off] : 0;
    __syncthreads();
    s[t] += v;
    __syncthreads();
  }
  int run = (t > 0) ? s[t - 1] : 0;
  for (int i = b0; i < b1; i++){
    int dg = degi[i];
    ptr[i] = run; cur[i] = run; run += dg;
    dis[i] = dg > 0 ? rsqrtf((float)dg) : 0.f;
  }
  if (t == 1023) ptr[Nn] = s[1023];
}

__global__ void k_scatter(const int* __restrict__ src, const int* __restrict__ dst,
    int* __restrict__ cur, int* __restrict__ csr_src){
  int e = blockIdx.x * blockDim.x + threadIdx.x;
  if (e >= EALLe) return;
  int pos = atomicAdd(&cur[dst[e]], 1);
  csr_src[pos] = src[e];
}

// GCN SpMM + relu, float4 gathers, 2-deep unroll for ILP
__global__ __launch_bounds__(256) void k_gcn4(const unsigned short* __restrict__ x,
    const int* __restrict__ ptr, const int* __restrict__ src,
    const float* __restrict__ dis, float* __restrict__ out){
  __shared__ float wl[128];
  __shared__ int jl[128];
  __shared__ float red[5][40][8];
  int i = blockIdx.x, t = threadIdx.x;
  int p0 = ptr[i], p1 = ptr[i + 1];
  float* orow = out + (size_t)i * 300;
  if (p0 == p1){
    for (int f = t; f < 300; f += 256) orow[f] = 0.f;
    return;
  }
  int g = t / 40, c = t - g * 40;
  bool act = t < 240;
  float di = dis[i];
  float acc[8] = {};
  for (int base = p0; base < p1; base += 128){
    int k = base + t;
    if (t < 128 && k < p1){
      int j = src[k];
      jl[t] = j;
      wl[t] = di * dis[j];
    }
    __syncthreads();
    int lim = p1 - base; if (lim > 128) lim = 128;
    if (act){
      int q = g;
      for (; q + 6 < lim; q += 12){
        float w0 = wl[q], w1 = wl[q + 6];
        const unsigned short* x0 = x + (size_t)jl[q] * 320;
        const unsigned short* x1p = x + (size_t)jl[q + 6] * 320;
        union { f32x4 f; unsigned int u[4]; } U0, U1;
        U0.f = *(const f32x4*)&x0[8 * c];
        U1.f = *(const f32x4*)&x1p[8 * c];
#pragma unroll
        for (int h = 0; h < 4; h++){
          acc[2 * h]     += w0 * b2f_lo(U0.u[h]) + w1 * b2f_lo(U1.u[h]);
          acc[2 * h + 1] += w0 * b2f_hi(U0.u[h]) + w1 * b2f_hi(U1.u[h]);
        }
      }
      for (; q < lim; q += 6){
        float w = wl[q];
        const unsigned short* xr = x + (size_t)jl[q] * 320;
        union { f32x4 f; unsigned int u[4]; } U;
        U.f = *(const f32x4*)&xr[8 * c];
#pragma unroll
        for (int h = 0; h < 4; h++){
          acc[2 * h]     += w * b2f_lo(U.u[h]);
          acc[2 * h + 1] += w * b2f_hi(U.u[h]);
        }
      }
    }
    __syncthreads();
  }
  if (act && g > 0){
#pragma unroll
    for (int h = 0; h < 8; h++) red[g - 1][c][h] = acc[h];
  }
  __syncthreads();
  if (g == 0){
#pragma unroll
    for (int h = 0; h < 8; h++){
      float v = acc[h];
#pragma unroll
      for (int r = 0; r < 5; r++) v += red[r][c][h];
      acc[h] = fmaxf(v, 0.f);
    }
    int col0 = 8 * c;
    if (col0 + 8 <= 300){
      f32x4 o0 = { acc[0], acc[1], acc[2], acc[3] };
      f32x4 o1 = { acc[4], acc[5], acc[6], acc[7] };
      *(f32x4*)&orow[col0] = o0;
      *(f32x4*)&orow[col0 + 4] = o1;
    } else {
      for (int h = 0; h < 8 && col0 + h < 300; h++) orow[col0 + h] = acc[h];
    }
  }
}

// final GAT: fused x-copy + in-LDS edge weights + float4 gathers + wave-reduced den
__global__ __launch_bounds__(256) void k_gat4(const float* __restrict__ x1,
    const unsigned short* __restrict__ x1b,
    const int* __restrict__ ptr, const int* __restrict__ src,
    const float* __restrict__ s1, const float* __restrict__ s2,
    float* __restrict__ dout){
  __shared__ float wl[128];
  __shared__ int jl[128];
  __shared__ float red[2][75][8];
  __shared__ float dsum;
  int i = blockIdx.x, t = threadIdx.x;
  float* orow = dout + (size_t)i * 900;
  const float* xi = x1 + (size_t)i * 600;
  if (t < 75) ((f32x4*)orow)[t] = ((const f32x4*)xi)[t];
  int p0 = ptr[i], p1 = ptr[i + 1];
  if (p0 == p1){
    for (int f = t; f < 600; f += 256) orow[300 + f] = 0.f;
    return;
  }
  float s1i = s1[i];
  int g = t / 75, c = t - g * 75;
  bool act = t < 225;
  float acc[8] = {};
  float denp = 0.f;
  for (int base = p0; base < p1; base += 128){
    if (t < 128){
      int k = base + t;
      bool valid = k < p1;
      int j = valid ? src[k] : 0;
      jl[t] = j;
      wl[t] = valid ? expf(lrelu01(s1i + s2[j])) : 0.f;
    }
    __syncthreads();
    int lim = p1 - base; if (lim > 128) lim = 128;
    if (t < 64) denp += wl[t] + wl[t + 64];
    if (act){
      int q = g;
      for (; q + 3 < lim; q += 6){
        float w0 = wl[q], w1 = wl[q + 3];
        const unsigned short* x0 = x1b + (size_t)jl[q] * 600;
        const unsigned short* x1p = x1b + (size_t)jl[q + 3] * 600;
        union { f32x4 f; unsigned int u[4]; } U0, U1;
        U0.f = *(const f32x4*)&x0[8 * c];
        U1.f = *(const f32x4*)&x1p[8 * c];
#pragma unroll
        for (int h = 0; h < 4; h++){
          acc[2 * h]     += w0 * b2f_lo(U0.u[h]) + w1 * b2f_lo(U1.u[h]);
          acc[2 * h + 1] += w0 * b2f_hi(U0.u[h]) + w1 * b2f_hi(U1.u[h]);
        }
      }
      for (; q < lim; q += 3){
        float w = wl[q];
        const unsigned short* xj = x1b + (size_t)jl[q] * 600;
        union { f32x4 f; unsigned int u[4]; } U;
        U.f = *(const f32x4*)&xj[8 * c];
#pragma unroll
        for (int h = 0; h < 4; h++){
          acc[2 * h]     += w * b2f_lo(U.u[h]);
          acc[2 * h + 1] += w * b2f_hi(U.u[h]);
        }
      }
    }
    __syncthreads();
  }
  if (act && g > 0){
#pragma unroll
    for (int h = 0; h < 8; h++) red[g - 1][c][h] = acc[h];
  }
  if (t < 64){
    float dd[1] = { denp };
    wredsumN<1>(dd);
    if (t == 0) dsum = dd[0];
  }
  __syncthreads();
  if (g == 0){
    float invd = 1.f / dsum;
#pragma unroll
    for (int h = 0; h < 8; h++){
      float v = acc[h] + red[0][c][h] + red[1][c][h];
      acc[h] = fmaxf(v * invd, 0.f);
    }
    f32x4 o0 = { acc[0], acc[1], acc[2], acc[3] };
    f32x4 o1 = { acc[4], acc[5], acc[6], acc[7] };
    ((f32x4*)(orow + 300))[2 * c] = o0;
    ((f32x4*)(orow + 300))[2 * c + 1] = o1;
  }
}

// bf16 MFMA GEMM, 128x64 tile, 4 waves, 8 MFMA/wave/K-step
template<int EPI, int MIR>
__global__ __launch_bounds__(256) void k_gemm2(
    const unsigned short* __restrict__ Xb, int ldxb, int nrows,
    const unsigned short* __restrict__ Wb, int Kp, int M,
    const float* __restrict__ bias,
    const float* __restrict__ X2, int ldx2,
    const float* __restrict__ Xf, int ldxf,
    float* __restrict__ out, int ldo,
    unsigned short* __restrict__ mir, int ldmir){
  __shared__ unsigned short Xs[128][40];
  __shared__ unsigned short Ws[64][40];
  int t = threadIdx.x;
  int wv = t >> 6, lane = t & 63;
  int c0 = blockIdx.x * 64, r0 = blockIdx.y * 128;
  int sxr = t >> 1, sxk = (t & 1) * 16;    // X staging: row, 16-elem chunk
  int swr = t >> 2, swk = (t & 3) * 8;     // W staging: row, 8-elem chunk
  int gxr = r0 + sxr, gwr = c0 + swr;
  f32x4 acc[2][4] = {};
  for (int k0 = 0; k0 < Kp; k0 += 32){
    short8 xv0 = {0,0,0,0,0,0,0,0}, xv1 = {0,0,0,0,0,0,0,0};
    short8 wv8 = {0,0,0,0,0,0,0,0};
    if (gxr < nrows){
      xv0 = *(const short8*)&Xb[(size_t)gxr * ldxb + k0 + sxk];
      xv1 = *(const short8*)&Xb[(size_t)gxr * ldxb + k0 + sxk + 8];
    }
    if (gwr < M) wv8 = *(const short8*)&Wb[(size_t)gwr * Kp + k0 + swk];
    __syncthreads();
    *(short8*)&Xs[sxr][sxk] = xv0;
    *(short8*)&Xs[sxr][sxk + 8] = xv1;
    *(short8*)&Ws[swr][swk] = wv8;
    __syncthreads();
    int kk = (lane >> 4) * 8;
    int arow = wv * 32 + (lane & 15);
    short8 a0 = *(const short8*)&Xs[arow][kk];
    short8 a1 = *(const short8*)&Xs[arow + 16][kk];
#pragma unroll
    for (int j = 0; j < 4; j++){
      short8 bf = *(const short8*)&Ws[j * 16 + (lane & 15)][kk];
      acc[0][j] = __builtin_amdgcn_mfma_f32_16x16x32_bf16(a0, bf, acc[0][j], 0, 0, 0);
      acc[1][j] = __builtin_amdgcn_mfma_f32_16x16x32_bf16(a1, bf, acc[1][j], 0, 0, 0);
    }
  }
  int cbase = c0 + (lane & 15);
#pragma unroll
  for (int ir = 0; ir < 2; ir++){
    int rbase = r0 + wv * 32 + ir * 16 + (lane >> 4) * 4;
#pragma unroll
    for (int j = 0; j < 4; j++){
      int c = cbase + j * 16;
      if (c >= M) continue;
#pragma unroll
      for (int r = 0; r < 4; r++){
        int row = rbase + r;
        if (row >= nrows) continue;
        float v = acc[ir][j][r];
        float o;
        if (EPI == 0){
          o = fmaxf(v, 0.f);
        } else {
          float g = 1.f / (1.f + expf(-(v + bias[c])));
          o = g * X2[(size_t)row * ldx2 + c] + (1.f - g) * Xf[(size_t)row * ldxf + c];
        }
        out[(size_t)row * ldo + c] = o;
        if (MIR) mir[(size_t)row * ldmir + c] = f2b(o);
      }
    }
  }
}

// batched gat_e highway GEMM (64x64 tile, small K)
__global__ __launch_bounds__(256) void k_hwgemm(
    const unsigned short* __restrict__ xob,
    const unsigned short* __restrict__ hwwbA, const unsigned short* __restrict__ hwwbB,
    const float* __restrict__ hwbA, const float* __restrict__ hwbB,
    const float* __restrict__ outb, const float* __restrict__ proj,
    float* __restrict__ x1, unsigned short* __restrict__ x1b){
  __shared__ unsigned short Xs[64][40];
  __shared__ unsigned short Ws[64][40];
  int g = blockIdx.z;
  const unsigned short* Xb = xob + (size_t)g * Nn * 160;
  const unsigned short* Wb = g ? hwwbB : hwwbA;
  const float* bias = g ? hwbB : hwbA;
  const float* X2 = outb + (size_t)g * Nn * CHd;
  const float* Xf = proj + (g ? 450 : 0);
  float* outp = x1 + (g ? 450 : 300);
  unsigned short* mir = x1b + (g ? 450 : 300);
  int t = threadIdx.x;
  int wv = t >> 6, lane = t & 63;
  int c0 = blockIdx.x * 64, r0 = blockIdx.y * 64;
  int srow = t >> 2, skoff = (t & 3) * 8;
  int gxr = r0 + srow, gwr = c0 + srow;
  f32x4 acc[4] = {};
  for (int k0 = 0; k0 < 160; k0 += 32){
    short8 xv = {0,0,0,0,0,0,0,0};
    short8 wv8 = {0,0,0,0,0,0,0,0};
    if (gxr < Nn) xv = *(const short8*)&Xb[(size_t)gxr * 160 + k0 + skoff];
    if (gwr < 150) wv8 = *(const short8*)&Wb[(size_t)gwr * 160 + k0 + skoff];
    __syncthreads();
    *(short8*)&Xs[srow][skoff] = xv;
    *(short8*)&Ws[srow][skoff] = wv8;
    __syncthreads();
    int arow = wv * 16 + (lane & 15);
    int kk = (lane >> 4) * 8;
    short8 af = *(const short8*)&Xs[arow][kk];
#pragma unroll
    for (int j = 0; j < 4; j++){
      short8 bf = *(const short8*)&Ws[j * 16 + (lane & 15)][kk];
      acc[j] = __builtin_amdgcn_mfma_f32_16x16x32_bf16(af, bf, acc[j], 0, 0, 0);
    }
  }
  int rbase = r0 + wv * 16 + (lane >> 4) * 4;
  int cbase = c0 + (lane & 15);
#pragma unroll
  for (int j = 0; j < 4; j++){
    int c = cbase + j * 16;
    if (c >= 150) continue;
#pragma unroll
    for (int r = 0; r < 4; r++){
      int row = rbase + r;
      if (row >= Nn) continue;
      float v = acc[j][r];
      float gg = 1.f / (1.f + expf(-(v + bias[c])));
      float o = gg * X2[(size_t)row * CHd + c] + (1.f - gg) * Xf[(size_t)row * 600 + c];
      outp[(size_t)row * 600 + c] = o;
      mir[(size_t)row * 600 + c] = f2b(o);
    }
  }
}

// batched per-node precompute for both gat_e calls + fused xo->bf16 mirror
__global__ __launch_bounds__(64) void k_ndots2b(const float* __restrict__ proj,
    const float* __restrict__ h2r_ac, const float* __restrict__ et_ac,
    unsigned short* __restrict__ xob,
    unsigned short* __restrict__ xnb, float* __restrict__ pm,
    float* __restrict__ po, float* __restrict__ nv4){
  int n = blockIdx.x, g = blockIdx.y, lane = threadIdx.x;
  const float* ac = g ? et_ac : h2r_ac;
  const float* xm = proj + (g ? 300 : 150);
  const float* xo = proj + (g ? 450 : 0);
  const float* v2m = ac + (g ? 1 : 5) * CHd;
  const float* v2o = ac + (g ? 5 : 1) * CHd;
  const float* v3m = ac + (g ? 2 : 6) * CHd;
  const float* v3o = ac + (g ? 6 : 2) * CHd;
  const float* v4  = ac + 3 * CHd;
  bool m2 = lane < (CHd - 128);
  const float* mr = xm + (size_t)n * 600;
  const float* orw = xo + (size_t)n * 600;
  float m0 = mr[lane], m1 = mr[lane + 64], mv2 = m2 ? mr[lane + 128] : 0.f;
  float o0 = orw[lane], o1 = orw[lane + 64], o2 = m2 ? orw[lane + 128] : 0.f;
  unsigned short* xod = xob + (size_t)g * Nn * 160 + (size_t)n * 160;
  xod[lane] = f2b(o0);
  xod[lane + 64] = f2b(o1);
  if (m2) xod[lane + 128] = f2b(o2);
  if (lane < 10) xod[150 + lane] = 0;
  float s[4];
  s[0] = m0 * m0 + m1 * m1 + mv2 * mv2;
  s[1] = o0 * v2o[lane] + o1 * v2o[lane + 64] + (m2 ? o2 * v2o[lane + 128] : 0.f);
  s[2] = o0 * v3o[lane] + o1 * v3o[lane + 64] + (m2 ? o2 * v3o[lane + 128] : 0.f);
  s[3] = o0 * v4[lane]  + o1 * v4[lane + 64]  + (m2 ? o2 * v4[lane + 128]  : 0.f);
  wredsumN<4>(s);
  float inv = 1.f / fmaxf(sqrtf(s[0]), 1e-12f);
  float n0 = m0 * inv, n1 = m1 * inv, n2 = mv2 * inv;
  unsigned short* xr = xnb + (size_t)g * Nn * 152 + (size_t)n * 152;
  xr[lane] = f2b(n0); xr[lane + 64] = f2b(n1);
  if (m2) xr[lane + 128] = f2b(n2);
  float d[2];
  d[0] = n0 * v2m[lane] + n1 * v2m[lane + 64] + (m2 ? n2 * v2m[lane + 128] : 0.f);
  d[1] = n0 * v3m[lane] + n1 * v3m[lane + 64] + (m2 ? n2 * v3m[lane + 128] : 0.f);
  wredsumN<2>(d);
  if (!lane){
    pm[g * Nn + n] = d[0] + 0.25f * d[1];
    po[g * Nn + n] = s[1] + 0.25f * s[2];
    nv4[g * Nn + n] = s[3];
  }
}

// SINGLE-PASS edge kernel: exp-logit + class sums + direct class-bucket scatter.
__global__ __launch_bounds__(256) void k_edgescatter(const int* __restrict__ ei,
    const int* __restrict__ rel, const int* __restrict__ cih, const int* __restrict__ cit,
    const float* __restrict__ pm, const float* __restrict__ po,
    const float* __restrict__ ra1h, const float* __restrict__ ra1e,
    float* __restrict__ csum_p, int* __restrict__ ccur_p,
    int* __restrict__ crows, float* __restrict__ cw){
  __shared__ float ls[Cc];
  __shared__ int lcnt[Cc];
  __shared__ int lbase[Cc];
  int t = threadIdx.x, g = blockIdx.y;
  const int* im = ei + (g ? 0 : Ee);
  const int* io = ei + (g ? Ee : 0);
  const int* ci = g ? cit : cih;
  const float* ra1 = g ? ra1e : ra1h;
  const float* pmg = pm + g * Nn;
  const float* pog = po + g * Nn;
  float* csg = csum_p + g * Cc * 16;
  int* cug = ccur_p + g * Cc * 16;
  int* crg = crows + (size_t)g * Cc * CAP;
  float* cwg = cw + (size_t)g * Cc * CAP;
  int epb = (Ee + gridDim.x - 1) / gridDim.x;
  int e0 = blockIdx.x * epb, e1 = e0 + epb; if (e1 > Ee) e1 = Ee;
  for (int c = t; c < Cc; c += 256){ ls[c] = 0.f; lcnt[c] = 0; }
  __syncthreads();
  int myr[4], myc[4], myrow[4]; float myw[4]; int cnt = 0;
  for (int e = e0 + t; e < e1; e += 256){
    float v = lrelu01(pog[io[e]] + pmg[im[e]] + ra1[rel[e]]);
    float s = expf(v);
    int c = ci[e];
    atomicAdd(&ls[c], s);
    myr[cnt] = atomicAdd(&lcnt[c], 1);
    myc[cnt] = c; myw[cnt] = s; myrow[cnt] = im[im[e]];
    cnt++;
  }
  __syncthreads();
  for (int c = t; c < Cc; c += 256){
    if (lcnt[c]){
      lbase[c] = atomicAdd(&cug[c * 16], lcnt[c]);
      atomicAdd(&csg[c * 16], ls[c]);
    }
  }
  __syncthreads();
  for (int q = 0; q < cnt; q++){
    int c = myc[q];
    int pos = c * CAP + lbase[c] + myr[q];
    crg[pos] = myrow[q];
    cwg[pos] = myw[q];
  }
}

// class x_class accumulation: XSPL blocks per class; range = [c*CAP, c*CAP+len)
__global__ __launch_bounds__(192) void k_xclassBb(
    const int* __restrict__ ccur_p, const int* __restrict__ crows,
    const float* __restrict__ cw, const float* __restrict__ csum_p,
    const unsigned short* __restrict__ xnb, float* __restrict__ x_class){
  int g = blockIdx.y;
  int c = blockIdx.x / XSPL, sp = blockIdx.x % XSPL;
  int t = threadIdx.x;
  const int* crg = crows + (size_t)g * Cc * CAP;
  const float* cwg = cw + (size_t)g * Cc * CAP;
  const unsigned short* xng = xnb + (size_t)g * Nn * 152;
  float* xcg = x_class + g * Cc * CHd;
  int len = ccur_p[g * Cc * 16 + c * 16];
  if (len <= 0) return;
  int chunk = (len + XSPL - 1) / XSPL;
  int q0 = c * CAP + sp * chunk;
  int q1 = q0 + chunk;
  int qend = c * CAP + len;
  if (q1 > qend) q1 = qend;
  if (q0 >= q1) return;
  bool act = t < CHd;
  float inv = 1.f / csum_p[g * Cc * 16 + c * 16];
  float acc = 0.f;
  int k = q0;
  for (; k + 4 <= q1; k += 4){
    int r0 = crg[k], r1 = crg[k + 1], r2 = crg[k + 2], r3 = crg[k + 3];
    float w0 = cwg[k] * inv, w1 = cwg[k + 1] * inv, w2 = cwg[k + 2] * inv, w3 = cwg[k + 3] * inv;
    if (act){
      acc += w0 * b2f(xng[(size_t)r0 * 152 + t]) + w1 * b2f(xng[(size_t)r1 * 152 + t])
           + w2 * b2f(xng[(size_t)r2 * 152 + t]) + w3 * b2f(xng[(size_t)r3 * 152 + t]);
    }
  }
  for (; k < q1; k++){
    if (act) acc += cwg[k] * inv * b2f(xng[(size_t)crg[k] * 152 + t]);
  }
  if (act) atomicAdd(&xcg[c * CHd + t], acc);
}

// class-final step 1: one wave per (class, call)
__global__ __launch_bounds__(64) void k_ecb(const float* __restrict__ x_class,
    const float* __restrict__ h2r_ac, const float* __restrict__ et_ac,
    const float* __restrict__ nv4,
    const int* __restrict__ hcls, const int* __restrict__ tcls,
    float* __restrict__ vv){
  int c = blockIdx.x, g = blockIdx.y, lane = threadIdx.x;
  const float* xc = x_class + (size_t)g * Cc * CHd + (size_t)c * CHd;
  const float* acv = (g ? et_ac : h2r_ac) + 7 * CHd;
  bool m2 = lane < (CHd - 128);
  float s[1];
  s[0] = xc[lane] * acv[lane] + xc[lane + 64] * acv[lane + 64]
       + (m2 ? xc[lane + 128] * acv[lane + 128] : 0.f);
  wredsumN<1>(s);
  if (!lane){
    int ce = (g ? tcls : hcls)[c];
    vv[g * Cc + c] = lrelu01(s[0] + nv4[g * Nn + ce]);
  }
}

// class-final step 2: per call g, segment softmax over cls_ent -> gmv
__global__ __launch_bounds__(256) void k_gammab(const float* __restrict__ vv,
    const int* __restrict__ hcls, const int* __restrict__ tcls,
    float* __restrict__ gmv){
  __shared__ float v[Cc];
  __shared__ int ce[Cc];
  int t = threadIdx.x, g = blockIdx.x;
  const int* cls_ent = g ? tcls : hcls;
  if (t < Cc){
    v[t] = vv[g * Cc + t];
    ce[t] = cls_ent[t];
  }
  __syncthreads();
  if (t < Cc){
    int sgm = ce[t];
    float m = -3.0e38f;
    for (int c2 = 0; c2 < Cc; c2++) if (ce[c2] == sgm) m = fmaxf(m, v[c2]);
    float sum = 0.f;
    for (int c2 = 0; c2 < Cc; c2++) if (ce[c2] == sgm) sum += expf(v[c2] - m);
    gmv[g * Cc + t] = expf(v[t] - m) / sum;
  }
}

// class-final step 3: parallel scatter outb[ce[c]] += gm[c] * x_class[c]
__global__ __launch_bounds__(256) void k_cfscatter(const float* __restrict__ x_class,
    const float* __restrict__ gmv,
    const int* __restrict__ hcls, const int* __restrict__ tcls,
    float* __restrict__ outb){
  int g = blockIdx.y;
  int idx = blockIdx.x * 256 + threadIdx.x;
  if (idx >= Cc * CHd) return;
  int c = idx / CHd, f = idx - c * CHd;
  int ce = (g ? tcls : hcls)[c];
  float val = gmv[g * Cc + c] * x_class[(size_t)g * Cc * CHd + idx];
  atomicAdd(&outb[(size_t)g * Nn * CHd + (size_t)ce * CHd + f], val);
}

// per node dot of x1b row with gat_ai / gat_aj — dword loads
__global__ __launch_bounds__(64) void k_s12(const unsigned short* __restrict__ x1b,
    const float* __restrict__ ai, const float* __restrict__ aj,
    float* __restrict__ s1, float* __restrict__ s2){
  int n = blockIdx.x, lane = threadIdx.x;
  const unsigned int* xr = (const unsigned int*)(x1b + (size_t)n * 600);
  float sa = 0.f, sb = 0.f;
#pragma unroll
  for (int u = 0; u < 5; u++){
    int d = lane + u * 64;
    if (d < 300){
      unsigned int w = xr[d];
      float xlo = b2f_lo(w), xhi = b2f_hi(w);
      sa += xlo * ai[2 * d] + xhi * ai[2 * d + 1];
      sb += xlo * aj[2 * d] + xhi * aj[2 * d + 1];
    }
  }
  float s[2] = { sa, sb };
  wredsumN<2>(s);
  if (!lane){ s1[n] = s[0]; s2[n] = s[1]; }
}

extern "C" void kernel_launch(void* const* d_in, const int* in_sizes, int n_in,
                              void* d_out, int out_size, void* d_ws, size_t ws_size,
                              hipStream_t stream) {
  const float* x_e    = (const float*)d_in[0];
  const int*   ei     = (const int*)d_in[1];
  const int*   rel    = (const int*)d_in[2];
  const int*   eall   = (const int*)d_in[3];
  const int*   cih    = (const int*)d_in[5];
  const int*   hcls   = (const int*)d_in[6];
  const int*   cit    = (const int*)d_in[7];
  const int*   tcls   = (const int*)d_in[8];
  const float* remb   = (const float*)d_in[9];
  const float* hw1w   = (const float*)d_in[10];
  const float* hw1b   = (const float*)d_in[11];
  const float* hw2w   = (const float*)d_in[12];
  const float* hw2b   = (const float*)d_in[13];
  const float* h2r_ac = (const float*)d_in[14];
  const float* h2r_ar = (const float*)d_in[15];
  const float* h2r_wh = (const float*)d_in[16];
  const float* h2r_wt = (const float*)d_in[17];
  const float* h2r_hww= (const float*)d_in[18];
  const float* h2r_hwb= (const float*)d_in[19];
  const float* et_ac  = (const float*)d_in[20];
  const float* et_ar  = (const float*)d_in[21];
  const float* et_wh  = (const float*)d_in[22];
  const float* et_wt  = (const float*)d_in[23];
  const float* et_hww = (const float*)d_in[24];
  const float* et_hwb = (const float*)d_in[25];
  const float* gai    = (const float*)d_in[26];
  const float* gaj    = (const float*)d_in[27];
  float* out = (float*)d_out;

  // ---- workspace allocator ----
  char* wsp = (char*)d_ws;
  auto alloc = [&](size_t nbytes) -> void* {
    void* p = (void*)wsp;
    wsp += (nbytes + 255) & ~(size_t)255;
    return p;
  };
  float* ra1h = (float*)alloc(Rr * 4);
  float* ra1e = (float*)alloc(Rr * 4);
  float* dis  = (float*)alloc(Nn * 4);
  int* degi    = (int*)alloc(Nn * 4);
  int* csr_ptr = (int*)alloc((Nn + 1) * 4);
  int* csr_cur = (int*)alloc(Nn * 4);
  int* csr_src = (int*)alloc((size_t)EALLe * 4);
  float* x1  = (float*)alloc((size_t)Nn * 600 * 4);
  float* pm  = (float*)alloc(2 * Nn * 4);
  float* po  = (float*)alloc(2 * Nn * 4);
  float* nv4 = (float*)alloc(2 * Nn * 4);
  float* csum_p = (float*)alloc(2 * Cc * 16 * 4);
  int*   ccur_p = (int*)alloc(2 * Cc * 16 * 4);
  float* x_class = (float*)alloc(2 * Cc * CHd * 4);
  size_t zregion = (size_t)((char*)x_class + ((2 * Cc * CHd * 4 + 255) & ~255)) - (size_t)(char*)csum_p;
  int*   crows  = (int*)alloc((size_t)2 * Cc * CAP * 4);
  float* cw     = (float*)alloc((size_t)2 * Cc * CAP * 4);
  float* s1v = (float*)alloc(Nn * 4);
  float* s2v = (float*)alloc(Nn * 4);
  float* vv  = (float*)alloc(2 * Cc * 4);
  float* gmv = (float*)alloc(2 * Cc * 4);
  unsigned short* arenaA = (unsigned short*)alloc((size_t)Nn * 320 * 2);
  unsigned short* arenaB = (unsigned short*)alloc((size_t)Nn * 320 * 2);
  unsigned short* x1b    = (unsigned short*)alloc(((size_t)Nn * 600 + 64) * 2);
  unsigned short* w1b    = (unsigned short*)alloc((size_t)300 * 320 * 2);
  unsigned short* w2b    = (unsigned short*)alloc((size_t)300 * 320 * 2);
  unsigned short* wcatb  = (unsigned short*)alloc((size_t)600 * 320 * 2);
  unsigned short* hwwbA  = (unsigned short*)alloc((size_t)150 * 160 * 2);
  unsigned short* hwwbB  = (unsigned short*)alloc((size_t)150 * 160 * 2);
  unsigned short* xob = arenaA;   // 2 x Nn x 160 bf16 (alias)
  unsigned short* xnb = arenaB;   // 2 x Nn x 152 bf16

  // d_out staging layout (all dead before k_gat4 rewrites d_out)
  float* h1   = out;
  float* gbuf = out + (size_t)Nn * EHd;
  float* proj = out;
  float* outb = out + (size_t)Nn * 600;

  // ---- prologue ----
  hipMemsetAsync(degi, 0, Nn * 4, stream);
  hipMemsetAsync(csum_p, 0, zregion, stream);
  hipMemsetAsync(outb, 0, (size_t)2 * Nn * CHd * 4, stream);
  k_rnorm<<<Rr, 64, 0, stream>>>(remb, h2r_ar, et_ar, ra1h, ra1e);
  k_count<<<cdiv_h(EALLe, 256), 256, 0, stream>>>(eall + EALLe, degi);
  k_scan<<<1, 1024, 0, stream>>>(degi, csr_ptr, csr_cur, dis);
  k_scatter<<<cdiv_h(EALLe, 256), 256, 0, stream>>>(eall, eall + EALLe, csr_cur, csr_src);
  {
    Cvt8 cv;
    cv.s[0] = hw1w;    cv.d[0] = w1b;                         cv.nc[0] = 300; cv.lds[0] = 300; cv.ldp[0] = 320;
    cv.s[1] = hw2w;    cv.d[1] = w2b;                         cv.nc[1] = 300; cv.lds[1] = 300; cv.ldp[1] = 320;
    cv.s[2] = h2r_wh;  cv.d[2] = wcatb + (size_t)0   * 320;   cv.nc[2] = 300; cv.lds[2] = 300; cv.ldp[2] = 320;
    cv.s[3] = h2r_wt;  cv.d[3] = wcatb + (size_t)150 * 320;   cv.nc[3] = 300; cv.lds[3] = 300; cv.ldp[3] = 320;
    cv.s[4] = et_wh;   cv.d[4] = wcatb + (size_t)300 * 320;   cv.nc[4] = 300; cv.lds[4] = 300; cv.ldp[4] = 320;
    cv.s[5] = et_wt;   cv.d[5] = wcatb + (size_t)450 * 320;   cv.nc[5] = 300; cv.lds[5] = 300; cv.ldp[5] = 320;
    cv.s[6] = h2r_hww; cv.d[6] = hwwbA;                       cv.nc[6] = 150; cv.lds[6] = 150; cv.ldp[6] = 160;
    cv.s[7] = et_hww;  cv.d[7] = hwwbB;                       cv.nc[7] = 150; cv.lds[7] = 150; cv.ldp[7] = 160;
    cv.r0[0] = 0;    cv.r0[1] = 300;  cv.r0[2] = 600;  cv.r0[3] = 750;
    cv.r0[4] = 900;  cv.r0[5] = 1050; cv.r0[6] = 1200; cv.r0[7] = 1350; cv.r0[8] = 1500;
    k_f2ball<<<1500, 64, 0, stream>>>(cv);
  }
  k_f2b<<<Nn, 64, 0, stream>>>(x_e, 300, 300, arenaA, 320);

  // ---- GCN + highway x2 (128-row MFMA GEMMs) ----
  k_gcn4<<<Nn, 256, 0, stream>>>(arenaA, csr_ptr, csr_src, dis, gbuf);
  k_gemm2<1,1><<<dim3(5, cdiv_h(Nn, 128)), 256, 0, stream>>>(
      arenaA, 320, Nn, w1b, 320, 300, hw1b, gbuf, 300, x_e, 300, h1, 300, arenaB, 320);
  k_gcn4<<<Nn, 256, 0, stream>>>(arenaB, csr_ptr, csr_src, dis, gbuf);
  k_gemm2<1,1><<<dim3(5, cdiv_h(Nn, 128)), 256, 0, stream>>>(
      arenaB, 320, Nn, w2b, 320, 300, hw2b, gbuf, 300, h1, 300, x1, 600, x1b, 600);

  // ---- batched projections ----
  k_gemm2<0,0><<<dim3(10, cdiv_h(Nn, 128)), 256, 0, stream>>>(
      x1b, 600, Nn, wcatb, 320, 600, nullptr, nullptr, 0, nullptr, 0, proj, 600,
      nullptr, 0);

  // ---- gat_e: both calls batched per kernel ----
  k_ndots2b<<<dim3(Nn, 2), 64, 0, stream>>>(proj, h2r_ac, et_ac, xob, xnb, pm, po, nv4);
  k_edgescatter<<<dim3(CB, 2), 256, 0, stream>>>(ei, rel, cih, cit, pm, po, ra1h, ra1e,
                                                 csum_p, ccur_p, crows, cw);
  k_xclassBb<<<dim3(Cc * XSPL, 2), 192, 0, stream>>>(ccur_p, crows, cw, csum_p,
                                                     xnb, x_class);
  k_ecb<<<dim3(Cc, 2), 64, 0, stream>>>(x_class, h2r_ac, et_ac, nv4, hcls, tcls, vv);
  k_gammab<<<2, 256, 0, stream>>>(vv, hcls, tcls, gmv);
  k_cfscatter<<<dim3(cdiv_h(Cc * CHd, 256), 2), 256, 0, stream>>>(
      x_class, gmv, hcls, tcls, outb);
  k_hwgemm<<<dim3(3, cdiv_h(Nn, 64), 2), 256, 0, stream>>>(
      xob, hwwbA, hwwbB, h2r_hwb, et_hwb, outb, proj, x1, x1b);

  // ---- final GAT ----
  k_s12<<<Nn, 64, 0, stream>>>(x1b, gai, gaj, s1v, s2v);
  k_gat4<<<Nn, 256, 0, stream>>>(x1, x1b, csr_ptr, csr_src, s1v, s2v, out);
}